// Round 1
// 1185.581 us; speedup vs baseline: 1.1380x; 1.1380x over previous
//
#include <hip/hip_runtime.h>
#include <math.h>

// B=16, C=128, X=128, Y=128, heads=8, dh=32, inner=256
// ws layout (float offsets):
#define OFF_MU    0u          // [262144] per (b,c,x)
#define OFF_RSTD  262144u
#define OFF_WT    524288u     // wT[c=128][o=768]            (final_kernel)
#define OFF_WOT   622592u     // woT[cp=256][o=128]          (final_kernel)
#define OFF_CTXA  655360u     // [bh=128][xg=16][1056] atomic partials (U 1024 + sexp 32)
#define OFF_CTXS  2818048u    // [bh=128][1024] scaled context
#define OFF_WSPL  2949120u    // 3 bf16 planes of permuted k/v weights:
                              // plane p: ushort[512 rows][128 c], row = blk*128 + ol,
                              // ol: [k h0 d0-31 | k h1 | v h0 | v h1] per blk
                              // 196608 ushort = 98304 floats -> total 3047424 floats

typedef __attribute__((ext_vector_type(8))) short bf16x8;
typedef __attribute__((ext_vector_type(4))) float f32x4;

// ---------------- prep: weight transposes + bf16 3-way split ----------------
__global__ void prep_kernel(const float* __restrict__ wqkv,
                            const float* __restrict__ wout,
                            float* __restrict__ ws) {
  int idx = blockIdx.x * 256 + threadIdx.x;   // 768 blocks -> 196608
  if (idx < 98304) {
    int o = idx >> 7, c = idx & 127;
    ws[OFF_WT + (unsigned)c * 768u + (unsigned)o] = wqkv[idx];
  } else if (idx < 131072) {
    int j = idx - 98304;
    int o = j >> 8, cp = j & 255;
    ws[OFF_WOT + (unsigned)cp * 128u + (unsigned)o] = wout[j];
  } else {
    // k/v weight rows, permuted per-blk, split into 3 truncated-bf16 planes
    int j = idx - 131072;            // 0..65535
    int row = j >> 7, c = j & 127;   // row 0..511
    int blk = row >> 7, ol = row & 127;
    int hh = (ol >> 5) & 1;
    int src = ((ol & 64) ? 512 : 256) + (2 * blk + hh) * 32 + (ol & 31);
    float v = wqkv[src * 128 + c];
    unsigned int u = __float_as_uint(v);
    float r1 = v - __uint_as_float(u & 0xffff0000u);
    unsigned int u1 = __float_as_uint(r1);
    float r2 = r1 - __uint_as_float(u1 & 0xffff0000u);
    unsigned int u2 = __float_as_uint(r2);
    unsigned short* wp = (unsigned short*)(ws + OFF_WSPL);
    wp[j]          = (unsigned short)(u >> 16);
    wp[65536 + j]  = (unsigned short)(u1 >> 16);
    wp[131072 + j] = (unsigned short)(u2 >> 16);
  }
}

// ---------------- LN0 stats per (b,c,x) row over y ----------------
__global__ void ln0_stats_kernel(const float* __restrict__ fmap,
                                 float* __restrict__ ws) {
  const int wid = threadIdx.x >> 6, lane = threadIdx.x & 63;
  const int row = blockIdx.x * 4 + wid;       // < 262144
  const float* p = fmap + (size_t)row * 128;
  float a0 = p[lane], a1 = p[lane + 64];
  double s = (double)a0 + (double)a1;
  double q = (double)a0 * a0 + (double)a1 * a1;
  #pragma unroll
  for (int off = 32; off; off >>= 1) {
    s += __shfl_xor(s, off);
    q += __shfl_xor(q, off);
  }
  if (lane == 0) {
    double mu = s * (1.0 / 128.0);
    double var = q * (1.0 / 128.0) - mu * mu;
    ws[OFF_MU + row] = (float)mu;
    ws[OFF_RSTD + row] = (float)(1.0 / sqrt(var + 1e-5));
  }
}

// ---------------- K1: all-heads K/V + context partials, one block per (b,x) ----------------
// MFMA (split-bf16 x6) version of the 128x128x128 qkv matmul per blk.
// LDS floats: pb[64][36]@0 (aliases fm f32 chunk [32][128]@0), vb@2304, vss@4608,
// ser@4864, rnS@5120, planes 3x[128][20]@5184 (aliased by red[512][16]@5184),
// muS@13376, rsS@13504, g0S@13632, b0S@13760 -> 13888 floats = 55.5 KB
__launch_bounds__(512, 4)
__global__ void kv_ctx_kernel(const float* __restrict__ fmap,
                              const float* __restrict__ g0,
                              const float* __restrict__ b0,
                              float* __restrict__ ws) {
  __shared__ float sm[13888];
  const int x = blockIdx.x, b = blockIdx.y, t = threadIdx.x;
  const int wave = t >> 6, lane = t & 63;
  const int ln = lane & 15, kb = lane >> 4;   // MFMA fragment coords
  const int or2 = wave >> 1, yc = wave & 1;   // wave tile: 2 o-tiles x 4 y-tiles
  const int dt = lane >> 3, et = lane & 7;    // U-loop coords (unchanged)
  const int xg = x >> 3;

  float* pb  = sm;            // [64][36]  exp(k) for one (head, y-half)
  float* vb  = sm + 2304;     // [64][36]  raw v
  float* vss = sm + 4608;     // [4][64]   v sumsq partials
  float* ser = sm + 4864;     // [8][8][4] sexp partials
  float* rnS = sm + 5120;     // [64]
  float* red = sm + 5184;     // [512][16] U-reduce scratch (aliases planes)
  float* pls = sm + 5184;     // 3 planes x [128 y][20 dw] packed bf16 pairs
  float* muS = sm + 13376;
  float* rsS = sm + 13504;
  float* g0S = sm + 13632;
  float* b0S = sm + 13760;
  float* fmS = sm;            // [32][128] f32 LN0 chunk (aliases pb/vb)

  if (t < 128) {
    muS[t] = ws[OFF_MU + (unsigned)((b * 128 + t) * 128 + x)];
    rsS[t] = ws[OFF_RSTD + (unsigned)((b * 128 + t) * 128 + x)];
  } else if (t < 256) g0S[t - 128] = g0[t - 128];
  else if (t < 384) b0S[t - 256] = b0[t - 256];

  const unsigned short* wspl = (const unsigned short*)(ws + OFF_WSPL);

  for (int blk = 0; blk < 4; ++blk) {           // blk covers heads 2*blk, 2*blk+1
    f32x4 acc[2][4];
    #pragma unroll
    for (int i = 0; i < 2; ++i)
      #pragma unroll
      for (int j = 0; j < 4; ++j) acc[i][j] = (f32x4){0.f, 0.f, 0.f, 0.f};

    for (int cc = 0; cc < 4; ++cc) {
      // A-fragment prefetch (weight planes, L2-resident, latency hidden by staging)
      bf16x8 af[2][3];
      #pragma unroll
      for (int ot = 0; ot < 2; ++ot)
        #pragma unroll
        for (int p = 0; p < 3; ++p)
          af[ot][p] = *(const bf16x8*)(wspl + p * 65536 +
              ((blk * 128 + or2 * 32 + ot * 16 + ln) * 128 + cc * 32 + kb * 8));

      __syncthreads();                          // fm/planes regions free
      #pragma unroll
      for (int it = 0; it < 2; ++it) {          // stage fm chunk, LN0 applied (f32)
        int idx4 = it * 512 + t;
        int c = idx4 >> 5, y4 = (idx4 & 31) * 4;
        int cg = cc * 32 + c;
        const float4 r = *(const float4*)(fmap + (((size_t)(b * 128 + cg)) * 128 + x) * 128 + y4);
        float mu = muS[cg], rs = rsS[cg];
        float4 g = *(const float4*)(g0S + y4);
        float4 be = *(const float4*)(b0S + y4);
        float4 o;
        o.x = (r.x - mu) * rs * g.x + be.x;
        o.y = (r.y - mu) * rs * g.y + be.y;
        o.z = (r.z - mu) * rs * g.z + be.z;
        o.w = (r.w - mu) * rs * g.w + be.w;
        *(float4*)(fmS + c * 128 + y4) = o;
      }
      __syncthreads();                          // fm visible
      {                                         // transpose + 3-way bf16 split
        const int ty = t & 127, cg = t >> 7;    // each thread: 8 c at one y
        unsigned int d0[4], d1[4], d2[4];
        #pragma unroll
        for (int jj = 0; jj < 4; ++jj) {
          unsigned int h[2], m[2], l[2];
          #pragma unroll
          for (int e = 0; e < 2; ++e) {
            float v = fmS[(cg * 8 + jj * 2 + e) * 128 + ty];
            unsigned int u = __float_as_uint(v);
            float r1 = v - __uint_as_float(u & 0xffff0000u);
            unsigned int u1 = __float_as_uint(r1);
            float r2 = r1 - __uint_as_float(u1 & 0xffff0000u);
            h[e] = u >> 16; m[e] = u1 >> 16; l[e] = __float_as_uint(r2) >> 16;
          }
          d0[jj] = h[0] | (h[1] << 16);
          d1[jj] = m[0] | (m[1] << 16);
          d2[jj] = l[0] | (l[1] << 16);
        }
        float* pp = pls + ty * 20 + cg * 4;
        *reinterpret_cast<uint4*>(pp)        = make_uint4(d0[0], d0[1], d0[2], d0[3]);
        *reinterpret_cast<uint4*>(pp + 2560) = make_uint4(d1[0], d1[1], d1[2], d1[3]);
        *reinterpret_cast<uint4*>(pp + 5120) = make_uint4(d2[0], d2[1], d2[2], d2[3]);
      }
      __syncthreads();                          // planes visible
      // MFMA: D[o][y] += W[o][c] * fm[c][y], 6 split-products (hh,hm,mh,hl,mm,lh)
      #pragma unroll
      for (int yt = 0; yt < 4; ++yt) {
        const float* bp = pls + ((yc * 4 + yt) * 16 + ln) * 20 + kb * 4;
        bf16x8 B0 = *(const bf16x8*)(bp);
        bf16x8 B1 = *(const bf16x8*)(bp + 2560);
        bf16x8 B2 = *(const bf16x8*)(bp + 5120);
        #pragma unroll
        for (int ot = 0; ot < 2; ++ot) {
          f32x4 c = acc[ot][yt];
          c = __builtin_amdgcn_mfma_f32_16x16x32_bf16(af[ot][0], B0, c, 0, 0, 0);
          c = __builtin_amdgcn_mfma_f32_16x16x32_bf16(af[ot][0], B1, c, 0, 0, 0);
          c = __builtin_amdgcn_mfma_f32_16x16x32_bf16(af[ot][1], B0, c, 0, 0, 0);
          c = __builtin_amdgcn_mfma_f32_16x16x32_bf16(af[ot][0], B2, c, 0, 0, 0);
          c = __builtin_amdgcn_mfma_f32_16x16x32_bf16(af[ot][1], B1, c, 0, 0, 0);
          c = __builtin_amdgcn_mfma_f32_16x16x32_bf16(af[ot][2], B0, c, 0, 0, 0);
          acc[ot][yt] = c;
        }
      }
    }

    // acc layout (m89 C/D map): col y = ln, row d = ot*16 + kb*4 + r
    // wave roles: or2 0/1 = k heads, 2/3 = v heads; yc = y-half
    for (int hh = 0; hh < 2; ++hh) {            // head = blk*2 + hh
      float u[16], se[4];
      #pragma unroll
      for (int i = 0; i < 16; ++i) u[i] = 0.0f;
      se[0] = se[1] = se[2] = se[3] = 0.0f;

      for (int hf = 0; hf < 2; ++hf) {          // y halves of 64
        if (wave == hh * 2 + hf) {              // k rows: exp -> pb[y][d]
          #pragma unroll
          for (int ot = 0; ot < 2; ++ot)
            #pragma unroll
            for (int yt = 0; yt < 4; ++yt) {
              f32x4 a = acc[ot][yt];
              float4 p;
              p.x = __expf(a[0]); p.y = __expf(a[1]);
              p.z = __expf(a[2]); p.w = __expf(a[3]);
              *(float4*)(pb + (yt * 16 + ln) * 36 + ot * 16 + kb * 4) = p;
            }
        }
        if (wave == 4 + hh * 2 + hf) {          // v rows raw + sumsq partials
          #pragma unroll
          for (int yt = 0; yt < 4; ++yt) {
            f32x4 a0 = acc[0][yt], a1 = acc[1][yt];
            int yl = yt * 16 + ln;
            *(float4*)(vb + yl * 36 + kb * 4)      = make_float4(a0[0], a0[1], a0[2], a0[3]);
            *(float4*)(vb + yl * 36 + 16 + kb * 4) = make_float4(a1[0], a1[1], a1[2], a1[3]);
            float s = a0[0] * a0[0] + a0[1] * a0[1] + a0[2] * a0[2] + a0[3] * a0[3]
                    + a1[0] * a1[0] + a1[1] * a1[1] + a1[2] * a1[2] + a1[3] * a1[3];
            vss[kb * 64 + yl] = s;
          }
        }
        __syncthreads();
        if (t < 64) {                           // rn per y (v l2-norm reciprocal)
          float s2 = vss[t] + vss[64 + t] + vss[128 + t] + vss[192 + t];
          rnS[t] = 1.0f / fmaxf(sqrtf(s2), 1e-12f);
        }
        __syncthreads();
        #pragma unroll 2
        for (int yy = 0; yy < 8; ++yy) {        // U tile: (4d x 4e) per lane, wave=yseg
          int y = wave * 8 + yy;
          const float4 p = *(const float4*)(pb + y * 36 + dt * 4);
          float4 v = *(const float4*)(vb + y * 36 + et * 4);
          float rn = rnS[y];
          v.x *= rn; v.y *= rn; v.z *= rn; v.w *= rn;
          se[0] += p.x; se[1] += p.y; se[2] += p.z; se[3] += p.w;
          u[0]  = fmaf(p.x, v.x, u[0]);  u[1]  = fmaf(p.x, v.y, u[1]);
          u[2]  = fmaf(p.x, v.z, u[2]);  u[3]  = fmaf(p.x, v.w, u[3]);
          u[4]  = fmaf(p.y, v.x, u[4]);  u[5]  = fmaf(p.y, v.y, u[5]);
          u[6]  = fmaf(p.y, v.z, u[6]);  u[7]  = fmaf(p.y, v.w, u[7]);
          u[8]  = fmaf(p.z, v.x, u[8]);  u[9]  = fmaf(p.z, v.y, u[9]);
          u[10] = fmaf(p.z, v.z, u[10]); u[11] = fmaf(p.z, v.w, u[11]);
          u[12] = fmaf(p.w, v.x, u[12]); u[13] = fmaf(p.w, v.y, u[13]);
          u[14] = fmaf(p.w, v.z, u[14]); u[15] = fmaf(p.w, v.w, u[15]);
        }
        __syncthreads();                        // before pbuf/vbuf reuse
      }
      // write partial tiles into red (aliases planes region, dead until next cc stage)
      *(float4*)(red + t * 16 + 0)  = make_float4(u[0], u[1], u[2], u[3]);
      *(float4*)(red + t * 16 + 4)  = make_float4(u[4], u[5], u[6], u[7]);
      *(float4*)(red + t * 16 + 8)  = make_float4(u[8], u[9], u[10], u[11]);
      *(float4*)(red + t * 16 + 12) = make_float4(u[12], u[13], u[14], u[15]);
      if (et == 0)
        *(float4*)(ser + (wave * 8 + dt) * 4) = make_float4(se[0], se[1], se[2], se[3]);
      __syncthreads();
      {
        const int tile = t >> 3;
        const int i0 = (t & 7) * 2;
        float s0 = 0.0f, s1 = 0.0f;
        #pragma unroll
        for (int w = 0; w < 8; ++w) {
          s0 += red[(w * 64 + tile) * 16 + i0];
          s1 += red[(w * 64 + tile) * 16 + i0 + 1];
        }
        const int d = (tile >> 3) * 4 + (i0 >> 2);
        const int e = (tile & 7) * 4 + (i0 & 3);
        float* ca = ws + OFF_CTXA + ((size_t)(b * 8 + blk * 2 + hh) * 16 + xg) * 1056;
        atomicAdd(ca + d * 32 + e, s0);
        atomicAdd(ca + d * 32 + e + 1, s1);
        if (t < 32) {
          float ss = 0.0f;
          #pragma unroll
          for (int w = 0; w < 8; ++w) ss += ser[(w * 8 + (t >> 2)) * 4 + (t & 3)];
          atomicAdd(ca + 1024 + t, ss);
        }
      }
    }
  }
}

// ---------------- reduce x-group partials, fold scales ----------------
__global__ void ctx_reduce_kernel(float* __restrict__ ws) {
  __shared__ float sume[32];
  const int bh = blockIdx.x, t = threadIdx.x;
  const float* ca = ws + OFF_CTXA + (size_t)bh * 16 * 1056;
  if (t < 32) {
    double a = 0.0;
    #pragma unroll
    for (int xg = 0; xg < 16; ++xg) a += ca[xg * 1056 + 1024 + t];
    sume[t] = (float)a;
  }
  __syncthreads();
  const double sb = (1.0 / 16384.0) * 0.17677669529663688;  // inv^2 * dh^-0.5
  #pragma unroll
  for (int i = 0; i < 4; ++i) {
    int de = t + 256 * i;
    double a = 0.0;
    #pragma unroll
    for (int xg = 0; xg < 16; ++xg) a += ca[xg * 1056 + de];
    ws[OFF_CTXS + (size_t)bh * 1024 + de] = (float)(a * sb / (double)sume[de >> 5]);
  }
}

// ---------------- final: Q matmul -> softmax -> q@ctx -> gelu -> out-conv -> LN1 ----------------
// LDS floats: fm[32][128]@0, wq/woS[32][128]@4096 (red_s@0/red_q@4096 at LN1),
// qh[32][132]@8192, ctxS[1024]@12416, muS@13440,rsS,g0S,b0S, lnm@13952, lnr@14080 -> 14208 = 56.8 KB
__launch_bounds__(512, 4)
__global__ void final_kernel(const float* __restrict__ fmap,
                             const float* __restrict__ g0,
                             const float* __restrict__ b0,
                             const float* __restrict__ g1,
                             const float* __restrict__ b1,
                             const float* __restrict__ ws,
                             float* __restrict__ out) {
  __shared__ float sm[14208];
  const int x = blockIdx.x, b = blockIdx.y, t = threadIdx.x;
  const int wave = t >> 6, lane = t & 63;
  const int og = (wave >> 1) * 4 + (lane >> 4);  // 0..15
  const int yg = (wave & 1) * 16 + (lane & 15);  // 0..31
  const int yq = t & 127, eg = t >> 7;           // qctx mapping
  float* fmS = sm;
  float* wS  = sm + 4096;
  float* qh  = sm + 8192;     // [32][132]
  float* ctxS = sm + 12416;
  float* muS = sm + 13440;
  float* rsS = sm + 13568;
  float* g0S = sm + 13696;
  float* b0S = sm + 13824;
  float* lnm = sm + 13952;
  float* lnr = sm + 14080;

  if (t < 128) {
    muS[t] = ws[OFF_MU + (unsigned)((b * 128 + t) * 128 + x)];
    rsS[t] = ws[OFF_RSTD + (unsigned)((b * 128 + t) * 128 + x)];
  } else if (t < 256) g0S[t - 128] = g0[t - 128];
  else if (t < 384) b0S[t - 256] = b0[t - 256];

  float o2[8][4];
  #pragma unroll
  for (int i = 0; i < 8; ++i)
    #pragma unroll
    for (int j = 0; j < 4; ++j) o2[i][j] = 0.0f;

  for (int qblk = 0; qblk < 2; ++qblk) {
    float qa[8][4];
    #pragma unroll
    for (int i = 0; i < 8; ++i)
      #pragma unroll
      for (int j = 0; j < 4; ++j) qa[i][j] = 0.0f;

    for (int cc = 0; cc < 4; ++cc) {
      __syncthreads();
      #pragma unroll
      for (int it = 0; it < 2; ++it) {
        int idx4 = it * 512 + t;
        int c = idx4 >> 5, y4 = (idx4 & 31) * 4;
        int cg = cc * 32 + c;
        const float4 r = *(const float4*)(fmap + (((size_t)(b * 128 + cg)) * 128 + x) * 128 + y4);
        float mu = muS[cg], rs = rsS[cg];
        float4 g = *(const float4*)(g0S + y4);
        float4 be = *(const float4*)(b0S + y4);
        float4 o;
        o.x = (r.x - mu) * rs * g.x + be.x;
        o.y = (r.y - mu) * rs * g.y + be.y;
        o.z = (r.z - mu) * rs * g.z + be.z;
        o.w = (r.w - mu) * rs * g.w + be.w;
        *(float4*)(fmS + c * 128 + y4) = o;
      }
      #pragma unroll
      for (int it = 0; it < 2; ++it) {
        int idx4 = it * 512 + t;
        int c = idx4 >> 5, rr = (idx4 & 31) * 4;
        int o = qblk * 128 + rr;
        *(float4*)(wS + c * 128 + rr) = *(const float4*)(ws + OFF_WT + (size_t)(cc * 32 + c) * 768 + o);
      }
      __syncthreads();
      #pragma unroll 8
      for (int c = 0; c < 32; ++c) {
        const float4 w0 = *(const float4*)(wS + c * 128 + og * 8);
        const float4 w1 = *(const float4*)(wS + c * 128 + og * 8 + 4);
        const float4 f  = *(const float4*)(fmS + c * 128 + yg * 4);
        const float wv[8] = {w0.x, w0.y, w0.z, w0.w, w1.x, w1.y, w1.z, w1.w};
        const float fv[4] = {f.x, f.y, f.z, f.w};
        #pragma unroll
        for (int i = 0; i < 8; ++i)
          #pragma unroll
          for (int j = 0; j < 4; ++j)
            qa[i][j] = fmaf(wv[i], fv[j], qa[i][j]);
      }
    }

    for (int hh = 0; hh < 4; ++hh) {            // head = qblk*4 + hh
      __syncthreads();                          // S1: qh/wS free of prior readers
      if ((og >> 2) == hh) {                    // transpose this head's q rows
        int dl = (og & 3) * 8;
        #pragma unroll
        for (int jj = 0; jj < 8; ++jj)
          *(float4*)(qh + (dl + jj) * 132 + yg * 4) =
              make_float4(qa[jj][0], qa[jj][1], qa[jj][2], qa[jj][3]);
      }
      if (t < 256)
        *(float4*)(ctxS + t * 4) =
            *(const float4*)(ws + OFF_CTXS + (size_t)(b * 8 + qblk * 4 + hh) * 1024 + t * 4);
      __syncthreads();                          // S2
      // softmax over d (no max-shift needed: |q| small) + q@ctx; e split 4 ways
      float ge[8];
      #pragma unroll
      for (int i = 0; i < 8; ++i) ge[i] = 0.0f;
      float ssum = 0.0f;
      #pragma unroll 4
      for (int dd = 0; dd < 32; ++dd) {
        float p = __expf(qh[dd * 132 + yq]);
        ssum += p;
        const float4 c0 = *(const float4*)(ctxS + dd * 32 + eg * 8);
        const float4 c1 = *(const float4*)(ctxS + dd * 32 + eg * 8 + 4);
        ge[0] = fmaf(p, c0.x, ge[0]); ge[1] = fmaf(p, c0.y, ge[1]);
        ge[2] = fmaf(p, c0.z, ge[2]); ge[3] = fmaf(p, c0.w, ge[3]);
        ge[4] = fmaf(p, c1.x, ge[4]); ge[5] = fmaf(p, c1.y, ge[5]);
        ge[6] = fmaf(p, c1.z, ge[6]); ge[7] = fmaf(p, c1.w, ge[7]);
      }
      const float rinv = 1.0f / ssum;
      // stage woS chunk for this head (wS free: q-matmul done, prev out-conv pre-S1)
      #pragma unroll
      for (int it = 0; it < 2; ++it) {
        int idx4 = it * 512 + t;
        int c = idx4 >> 5, o4 = (idx4 & 31) * 4;
        *(float4*)(wS + c * 128 + o4) =
            *(const float4*)(ws + OFF_WOT + (size_t)(qblk * 128 + hh * 32 + c) * 128 + o4);
      }
      __syncthreads();                          // S3: all qh reads done
      #pragma unroll
      for (int i = 0; i < 8; ++i) {             // gelu (erf), write in place
        float v = ge[i] * rinv;
        qh[(eg * 8 + i) * 132 + yq] = 0.5f * v * (1.0f + erff(v * 0.70710678118654752f));
      }
      __syncthreads();                          // S4: gel + woS visible
      #pragma unroll 4
      for (int cp = 0; cp < 32; ++cp) {         // out-conv partial accumulate
        const float4 w0 = *(const float4*)(wS + cp * 128 + og * 8);
        const float4 w1 = *(const float4*)(wS + cp * 128 + og * 8 + 4);
        const float4 gl = *(const float4*)(qh + cp * 132 + yg * 4);
        const float wv[8] = {w0.x, w0.y, w0.z, w0.w, w1.x, w1.y, w1.z, w1.w};
        const float gv[4] = {gl.x, gl.y, gl.z, gl.w};
        #pragma unroll
        for (int i = 0; i < 8; ++i)
          #pragma unroll
          for (int j = 0; j < 4; ++j)
            o2[i][j] = fmaf(wv[i], gv[j], o2[i][j]);
      }
    }
  }

  // ---- LN1 over y per o-row ----
  __syncthreads();
  #pragma unroll
  for (int oo = 0; oo < 8; ++oo) {
    float s = 0.0f, q = 0.0f;
    #pragma unroll
    for (int j = 0; j < 4; ++j) { float v = o2[oo][j]; s += v; q = fmaf(v, v, q); }
    sm[(og * 8 + oo) * 32 + yg] = s;            // red_s @ fm region
    sm[4096 + (og * 8 + oo) * 32 + yg] = q;     // red_q @ w region
  }
  __syncthreads();
  if (t < 128) {
    double s = 0.0, q = 0.0;
    #pragma unroll
    for (int i = 0; i < 32; ++i) { s += sm[t * 32 + i]; q += sm[4096 + t * 32 + i]; }
    double mu = s * (1.0 / 128.0);
    double var = q * (1.0 / 128.0) - mu * mu;
    lnm[t] = (float)mu;
    lnr[t] = (float)(1.0 / sqrt(var + 1e-5));
  }
  __syncthreads();
  const float4 g1v = *(const float4*)(g1 + yg * 4);
  const float4 b1v = *(const float4*)(b1 + yg * 4);
  #pragma unroll
  for (int oo = 0; oo < 8; ++oo) {
    int o = og * 8 + oo;
    float mu = lnm[o], rs = lnr[o];
    float4 r;
    r.x = (o2[oo][0] - mu) * rs * g1v.x + b1v.x;
    r.y = (o2[oo][1] - mu) * rs * g1v.y + b1v.y;
    r.z = (o2[oo][2] - mu) * rs * g1v.z + b1v.z;
    r.w = (o2[oo][3] - mu) * rs * g1v.w + b1v.w;
    *(float4*)(out + (((size_t)(b * 128 + o)) * 128 + x) * 128 + yg * 4) = r;
  }
}

extern "C" void kernel_launch(void* const* d_in, const int* in_sizes, int n_in,
                              void* d_out, int out_size, void* d_ws, size_t ws_size,
                              hipStream_t stream) {
  const float* fmap = (const float*)d_in[0];
  const float* g0   = (const float*)d_in[1];
  const float* b0   = (const float*)d_in[2];
  const float* wqkv = (const float*)d_in[3];
  const float* wout = (const float*)d_in[4];
  const float* g1   = (const float*)d_in[5];
  const float* b1   = (const float*)d_in[6];
  float* ws  = (float*)d_ws;
  float* out = (float*)d_out;

  hipMemsetAsync((char*)d_ws + (size_t)OFF_CTXA * 4, 0, (size_t)2162688 * 4, stream);
  prep_kernel<<<768, 256, 0, stream>>>(wqkv, wout, ws);
  ln0_stats_kernel<<<65536, 256, 0, stream>>>(fmap, ws);
  kv_ctx_kernel<<<dim3(128, 16), 512, 0, stream>>>(fmap, g0, b0, ws);
  ctx_reduce_kernel<<<128, 256, 0, stream>>>(ws);
  final_kernel<<<dim3(128, 16), 512, 0, stream>>>(fmap, g0, b0, g1, b1, ws, out);
}

// Round 2
// 1055.073 us; speedup vs baseline: 1.2787x; 1.1237x over previous
//
#include <hip/hip_runtime.h>
#include <math.h>

// B=16, C=128, X=128, Y=128, heads=8, dh=32, inner=256
// ws layout (float offsets):
#define OFF_MU    0u          // [262144] per (b,c,x)
#define OFF_RSTD  262144u
#define OFF_CTXA  655360u     // [bh=128][xg=16][1056] atomic partials (U 1024 + sexp 32)
#define OFF_CTXS  2818048u    // [bh=128][1024] scaled context
#define OFF_WSPL  2949120u    // 3 bf16 planes of permuted k/v weights:
                              // plane p: ushort[512 rows][128 c], row = blk*128 + ol,
                              // ol: [k h0 d0-31 | k h1 | v h0 | v h1] per blk
#define OFF_WQSPL 3047424u    // 3 bf16 planes of q weights: ushort[256 o][128 c] per plane
#define OFF_WOSPL 3096576u    // 3 bf16 planes of wout: ushort[128 o][256 cp] per plane
                              // end: 3145728 floats = 12.58 MB

typedef __attribute__((ext_vector_type(8))) short bf16x8;
typedef __attribute__((ext_vector_type(4))) float f32x4;

// ---------------- prep: bf16 3-way weight splits ----------------
__global__ void prep_kernel(const float* __restrict__ wqkv,
                            const float* __restrict__ wout,
                            float* __restrict__ ws) {
  int idx = blockIdx.x * 256 + threadIdx.x;   // 512 blocks -> 131072
  float v;
  unsigned short* wp;
  unsigned plane, slot;
  if (idx < 65536) {
    // k/v weight rows, permuted per-blk
    int row = idx >> 7, c = idx & 127;   // row 0..511
    int blk = row >> 7, ol = row & 127;
    int hh = (ol >> 5) & 1;
    int src = ((ol & 64) ? 512 : 256) + (2 * blk + hh) * 32 + (ol & 31);
    v = wqkv[src * 128 + c];
    wp = (unsigned short*)(ws + OFF_WSPL);
    plane = 65536; slot = (unsigned)idx;
  } else if (idx < 98304) {
    // q weights: rows o=0..255 of wqkv, layout [o][c]
    int j = idx - 65536;
    v = wqkv[j];
    wp = (unsigned short*)(ws + OFF_WQSPL);
    plane = 32768; slot = (unsigned)j;
  } else {
    // wout: [o=128][cp=256] row-major (native layout)
    int j = idx - 98304;
    v = wout[j];
    wp = (unsigned short*)(ws + OFF_WOSPL);
    plane = 32768; slot = (unsigned)j;
  }
  unsigned int u = __float_as_uint(v);
  float r1 = v - __uint_as_float(u & 0xffff0000u);
  unsigned int u1 = __float_as_uint(r1);
  float r2 = r1 - __uint_as_float(u1 & 0xffff0000u);
  unsigned int u2 = __float_as_uint(r2);
  wp[slot]             = (unsigned short)(u >> 16);
  wp[plane + slot]     = (unsigned short)(u1 >> 16);
  wp[2 * plane + slot] = (unsigned short)(u2 >> 16);
}

// ---------------- LN0 stats per (b,c,x) row over y ----------------
__global__ void ln0_stats_kernel(const float* __restrict__ fmap,
                                 float* __restrict__ ws) {
  const int wid = threadIdx.x >> 6, lane = threadIdx.x & 63;
  const int row = blockIdx.x * 4 + wid;       // < 262144
  const float* p = fmap + (size_t)row * 128;
  float a0 = p[lane], a1 = p[lane + 64];
  double s = (double)a0 + (double)a1;
  double q = (double)a0 * a0 + (double)a1 * a1;
  #pragma unroll
  for (int off = 32; off; off >>= 1) {
    s += __shfl_xor(s, off);
    q += __shfl_xor(q, off);
  }
  if (lane == 0) {
    double mu = s * (1.0 / 128.0);
    double var = q * (1.0 / 128.0) - mu * mu;
    ws[OFF_MU + row] = (float)mu;
    ws[OFF_RSTD + row] = (float)(1.0 / sqrt(var + 1e-5));
  }
}

// ---------------- K1: all-heads K/V + context partials, one block per (b,x) ----------------
// (unchanged from round 1)
__launch_bounds__(512, 4)
__global__ void kv_ctx_kernel(const float* __restrict__ fmap,
                              const float* __restrict__ g0,
                              const float* __restrict__ b0,
                              float* __restrict__ ws) {
  __shared__ float sm[13888];
  const int x = blockIdx.x, b = blockIdx.y, t = threadIdx.x;
  const int wave = t >> 6, lane = t & 63;
  const int ln = lane & 15, kb = lane >> 4;   // MFMA fragment coords
  const int or2 = wave >> 1, yc = wave & 1;   // wave tile: 2 o-tiles x 4 y-tiles
  const int dt = lane >> 3, et = lane & 7;    // U-loop coords
  const int xg = x >> 3;

  float* pb  = sm;            // [64][36]
  float* vb  = sm + 2304;     // [64][36]
  float* vss = sm + 4608;     // [4][64]
  float* ser = sm + 4864;     // [8][8][4]
  float* rnS = sm + 5120;     // [64]
  float* red = sm + 5184;     // [512][16] (aliases planes)
  float* pls = sm + 5184;     // 3 planes x [128 y][20 dw]
  float* muS = sm + 13376;
  float* rsS = sm + 13504;
  float* g0S = sm + 13632;
  float* b0S = sm + 13760;
  float* fmS = sm;            // [32][128] (aliases pb/vb)

  if (t < 128) {
    muS[t] = ws[OFF_MU + (unsigned)((b * 128 + t) * 128 + x)];
    rsS[t] = ws[OFF_RSTD + (unsigned)((b * 128 + t) * 128 + x)];
  } else if (t < 256) g0S[t - 128] = g0[t - 128];
  else if (t < 384) b0S[t - 256] = b0[t - 256];

  const unsigned short* wspl = (const unsigned short*)(ws + OFF_WSPL);

  for (int blk = 0; blk < 4; ++blk) {
    f32x4 acc[2][4];
    #pragma unroll
    for (int i = 0; i < 2; ++i)
      #pragma unroll
      for (int j = 0; j < 4; ++j) acc[i][j] = (f32x4){0.f, 0.f, 0.f, 0.f};

    for (int cc = 0; cc < 4; ++cc) {
      bf16x8 af[2][3];
      #pragma unroll
      for (int ot = 0; ot < 2; ++ot)
        #pragma unroll
        for (int p = 0; p < 3; ++p)
          af[ot][p] = *(const bf16x8*)(wspl + p * 65536 +
              ((blk * 128 + or2 * 32 + ot * 16 + ln) * 128 + cc * 32 + kb * 8));

      __syncthreads();
      #pragma unroll
      for (int it = 0; it < 2; ++it) {
        int idx4 = it * 512 + t;
        int c = idx4 >> 5, y4 = (idx4 & 31) * 4;
        int cg = cc * 32 + c;
        const float4 r = *(const float4*)(fmap + (((size_t)(b * 128 + cg)) * 128 + x) * 128 + y4);
        float mu = muS[cg], rs = rsS[cg];
        float4 g = *(const float4*)(g0S + y4);
        float4 be = *(const float4*)(b0S + y4);
        float4 o;
        o.x = (r.x - mu) * rs * g.x + be.x;
        o.y = (r.y - mu) * rs * g.y + be.y;
        o.z = (r.z - mu) * rs * g.z + be.z;
        o.w = (r.w - mu) * rs * g.w + be.w;
        *(float4*)(fmS + c * 128 + y4) = o;
      }
      __syncthreads();
      {                                         // transpose + 3-way bf16 split
        const int ty = t & 127, cg = t >> 7;
        unsigned int d0[4], d1[4], d2[4];
        #pragma unroll
        for (int jj = 0; jj < 4; ++jj) {
          unsigned int h[2], m[2], l[2];
          #pragma unroll
          for (int e = 0; e < 2; ++e) {
            float v = fmS[(cg * 8 + jj * 2 + e) * 128 + ty];
            unsigned int u = __float_as_uint(v);
            float r1 = v - __uint_as_float(u & 0xffff0000u);
            unsigned int u1 = __float_as_uint(r1);
            float r2 = r1 - __uint_as_float(u1 & 0xffff0000u);
            h[e] = u >> 16; m[e] = u1 >> 16; l[e] = __float_as_uint(r2) >> 16;
          }
          d0[jj] = h[0] | (h[1] << 16);
          d1[jj] = m[0] | (m[1] << 16);
          d2[jj] = l[0] | (l[1] << 16);
        }
        float* pp = pls + ty * 20 + cg * 4;
        *reinterpret_cast<uint4*>(pp)        = make_uint4(d0[0], d0[1], d0[2], d0[3]);
        *reinterpret_cast<uint4*>(pp + 2560) = make_uint4(d1[0], d1[1], d1[2], d1[3]);
        *reinterpret_cast<uint4*>(pp + 5120) = make_uint4(d2[0], d2[1], d2[2], d2[3]);
      }
      __syncthreads();
      #pragma unroll
      for (int yt = 0; yt < 4; ++yt) {
        const float* bp = pls + ((yc * 4 + yt) * 16 + ln) * 20 + kb * 4;
        bf16x8 B0 = *(const bf16x8*)(bp);
        bf16x8 B1 = *(const bf16x8*)(bp + 2560);
        bf16x8 B2 = *(const bf16x8*)(bp + 5120);
        #pragma unroll
        for (int ot = 0; ot < 2; ++ot) {
          f32x4 c = acc[ot][yt];
          c = __builtin_amdgcn_mfma_f32_16x16x32_bf16(af[ot][0], B0, c, 0, 0, 0);
          c = __builtin_amdgcn_mfma_f32_16x16x32_bf16(af[ot][0], B1, c, 0, 0, 0);
          c = __builtin_amdgcn_mfma_f32_16x16x32_bf16(af[ot][1], B0, c, 0, 0, 0);
          c = __builtin_amdgcn_mfma_f32_16x16x32_bf16(af[ot][0], B2, c, 0, 0, 0);
          c = __builtin_amdgcn_mfma_f32_16x16x32_bf16(af[ot][1], B1, c, 0, 0, 0);
          c = __builtin_amdgcn_mfma_f32_16x16x32_bf16(af[ot][2], B0, c, 0, 0, 0);
          acc[ot][yt] = c;
        }
      }
    }

    for (int hh = 0; hh < 2; ++hh) {
      float u[16], se[4];
      #pragma unroll
      for (int i = 0; i < 16; ++i) u[i] = 0.0f;
      se[0] = se[1] = se[2] = se[3] = 0.0f;

      for (int hf = 0; hf < 2; ++hf) {
        if (wave == hh * 2 + hf) {
          #pragma unroll
          for (int ot = 0; ot < 2; ++ot)
            #pragma unroll
            for (int yt = 0; yt < 4; ++yt) {
              f32x4 a = acc[ot][yt];
              float4 p;
              p.x = __expf(a[0]); p.y = __expf(a[1]);
              p.z = __expf(a[2]); p.w = __expf(a[3]);
              *(float4*)(pb + (yt * 16 + ln) * 36 + ot * 16 + kb * 4) = p;
            }
        }
        if (wave == 4 + hh * 2 + hf) {
          #pragma unroll
          for (int yt = 0; yt < 4; ++yt) {
            f32x4 a0 = acc[0][yt], a1 = acc[1][yt];
            int yl = yt * 16 + ln;
            *(float4*)(vb + yl * 36 + kb * 4)      = make_float4(a0[0], a0[1], a0[2], a0[3]);
            *(float4*)(vb + yl * 36 + 16 + kb * 4) = make_float4(a1[0], a1[1], a1[2], a1[3]);
            float s = a0[0] * a0[0] + a0[1] * a0[1] + a0[2] * a0[2] + a0[3] * a0[3]
                    + a1[0] * a1[0] + a1[1] * a1[1] + a1[2] * a1[2] + a1[3] * a1[3];
            vss[kb * 64 + yl] = s;
          }
        }
        __syncthreads();
        if (t < 64) {
          float s2 = vss[t] + vss[64 + t] + vss[128 + t] + vss[192 + t];
          rnS[t] = 1.0f / fmaxf(sqrtf(s2), 1e-12f);
        }
        __syncthreads();
        #pragma unroll 2
        for (int yy = 0; yy < 8; ++yy) {
          int y = wave * 8 + yy;
          const float4 p = *(const float4*)(pb + y * 36 + dt * 4);
          float4 v = *(const float4*)(vb + y * 36 + et * 4);
          float rn = rnS[y];
          v.x *= rn; v.y *= rn; v.z *= rn; v.w *= rn;
          se[0] += p.x; se[1] += p.y; se[2] += p.z; se[3] += p.w;
          u[0]  = fmaf(p.x, v.x, u[0]);  u[1]  = fmaf(p.x, v.y, u[1]);
          u[2]  = fmaf(p.x, v.z, u[2]);  u[3]  = fmaf(p.x, v.w, u[3]);
          u[4]  = fmaf(p.y, v.x, u[4]);  u[5]  = fmaf(p.y, v.y, u[5]);
          u[6]  = fmaf(p.y, v.z, u[6]);  u[7]  = fmaf(p.y, v.w, u[7]);
          u[8]  = fmaf(p.z, v.x, u[8]);  u[9]  = fmaf(p.z, v.y, u[9]);
          u[10] = fmaf(p.z, v.z, u[10]); u[11] = fmaf(p.z, v.w, u[11]);
          u[12] = fmaf(p.w, v.x, u[12]); u[13] = fmaf(p.w, v.y, u[13]);
          u[14] = fmaf(p.w, v.z, u[14]); u[15] = fmaf(p.w, v.w, u[15]);
        }
        __syncthreads();
      }
      *(float4*)(red + t * 16 + 0)  = make_float4(u[0], u[1], u[2], u[3]);
      *(float4*)(red + t * 16 + 4)  = make_float4(u[4], u[5], u[6], u[7]);
      *(float4*)(red + t * 16 + 8)  = make_float4(u[8], u[9], u[10], u[11]);
      *(float4*)(red + t * 16 + 12) = make_float4(u[12], u[13], u[14], u[15]);
      if (et == 0)
        *(float4*)(ser + (wave * 8 + dt) * 4) = make_float4(se[0], se[1], se[2], se[3]);
      __syncthreads();
      {
        const int tile = t >> 3;
        const int i0 = (t & 7) * 2;
        float s0 = 0.0f, s1 = 0.0f;
        #pragma unroll
        for (int w = 0; w < 8; ++w) {
          s0 += red[(w * 64 + tile) * 16 + i0];
          s1 += red[(w * 64 + tile) * 16 + i0 + 1];
        }
        const int d = (tile >> 3) * 4 + (i0 >> 2);
        const int e = (tile & 7) * 4 + (i0 & 3);
        float* ca = ws + OFF_CTXA + ((size_t)(b * 8 + blk * 2 + hh) * 16 + xg) * 1056;
        atomicAdd(ca + d * 32 + e, s0);
        atomicAdd(ca + d * 32 + e + 1, s1);
        if (t < 32) {
          float ss = 0.0f;
          #pragma unroll
          for (int w = 0; w < 8; ++w) ss += ser[(w * 8 + (t >> 2)) * 4 + (t & 3)];
          atomicAdd(ca + 1024 + t, ss);
        }
      }
    }
  }
}

// ---------------- reduce x-group partials, fold scales ----------------
__global__ void ctx_reduce_kernel(float* __restrict__ ws) {
  __shared__ float sume[32];
  const int bh = blockIdx.x, t = threadIdx.x;
  const float* ca = ws + OFF_CTXA + (size_t)bh * 16 * 1056;
  if (t < 32) {
    double a = 0.0;
    #pragma unroll
    for (int xg = 0; xg < 16; ++xg) a += ca[xg * 1056 + 1024 + t];
    sume[t] = (float)a;
  }
  __syncthreads();
  const double sb = (1.0 / 16384.0) * 0.17677669529663688;  // inv^2 * dh^-0.5
  #pragma unroll
  for (int i = 0; i < 4; ++i) {
    int de = t + 256 * i;
    double a = 0.0;
    #pragma unroll
    for (int xg = 0; xg < 16; ++xg) a += ca[xg * 1056 + de];
    ws[OFF_CTXS + (size_t)bh * 1024 + de] = (float)(a * sb / (double)sume[de >> 5]);
  }
}

// ---------------- final: Q matmul(MFMA) -> softmax -> q@ctx -> gelu -> out-conv(MFMA) -> LN1 ----------------
// LDS floats: fmS[32][128]@0 (red_s at LN1), pls 3x[128][20]@4096 (fm planes per cc,
// gel planes per head; red_q aliases @4096 at LN1), qh[32][132]@11776, ctxS[1024]@16000,
// muS@17024,rsS,g0S,b0S, lnm@17536, lnr@17664 -> 17792 floats = 71.2 KB (2 blocks/CU)
__launch_bounds__(512, 4)
__global__ void final_kernel(const float* __restrict__ fmap,
                             const float* __restrict__ g0,
                             const float* __restrict__ b0,
                             const float* __restrict__ g1,
                             const float* __restrict__ b1,
                             const float* __restrict__ ws,
                             float* __restrict__ out) {
  __shared__ float sm[17792];
  const int x = blockIdx.x, b = blockIdx.y, t = threadIdx.x;
  const int wave = t >> 6, lane = t & 63;
  const int ln = lane & 15, kb = lane >> 4;   // MFMA fragment coords
  const int or2 = wave >> 1, yc = wave & 1;   // wave tile: 2 o-tiles x 4 y-tiles
  const int yq = t & 127, eg = t >> 7;        // qctx/gelu mapping

  float* fmS = sm;            // [32][128]
  float* pls = sm + 4096;     // 3 planes x [128][20]
  float* qh  = sm + 11776;    // [32][132]
  float* ctxS = sm + 16000;   // [1024]
  float* muS = sm + 17024;
  float* rsS = sm + 17152;
  float* g0S = sm + 17280;
  float* b0S = sm + 17408;
  float* lnm = sm + 17536;
  float* lnr = sm + 17664;

  if (t < 128) {
    muS[t] = ws[OFF_MU + (unsigned)((b * 128 + t) * 128 + x)];
    rsS[t] = ws[OFF_RSTD + (unsigned)((b * 128 + t) * 128 + x)];
  } else if (t < 256) g0S[t - 128] = g0[t - 128];
  else if (t < 384) b0S[t - 256] = b0[t - 256];

  const unsigned short* wqspl = (const unsigned short*)(ws + OFF_WQSPL);
  const unsigned short* wospl = (const unsigned short*)(ws + OFF_WOSPL);

  f32x4 oacc[2][4];
  #pragma unroll
  for (int i = 0; i < 2; ++i)
    #pragma unroll
    for (int j = 0; j < 4; ++j) oacc[i][j] = (f32x4){0.f, 0.f, 0.f, 0.f};

  for (int qblk = 0; qblk < 2; ++qblk) {
    f32x4 qacc[2][4];
    #pragma unroll
    for (int i = 0; i < 2; ++i)
      #pragma unroll
      for (int j = 0; j < 4; ++j) qacc[i][j] = (f32x4){0.f, 0.f, 0.f, 0.f};

    for (int cc = 0; cc < 4; ++cc) {
      bf16x8 af[2][3];
      #pragma unroll
      for (int ot = 0; ot < 2; ++ot)
        #pragma unroll
        for (int p = 0; p < 3; ++p)
          af[ot][p] = *(const bf16x8*)(wqspl + p * 32768 +
              ((qblk * 128 + or2 * 32 + ot * 16 + ln) * 128 + cc * 32 + kb * 8));

      __syncthreads();                          // fmS/pls free of prior readers
      #pragma unroll
      for (int it = 0; it < 2; ++it) {          // stage fm chunk, LN0 applied (f32)
        int idx4 = it * 512 + t;
        int c = idx4 >> 5, y4 = (idx4 & 31) * 4;
        int cg = cc * 32 + c;
        const float4 r = *(const float4*)(fmap + (((size_t)(b * 128 + cg)) * 128 + x) * 128 + y4);
        float mu = muS[cg], rs = rsS[cg];
        float4 g = *(const float4*)(g0S + y4);
        float4 be = *(const float4*)(b0S + y4);
        float4 o;
        o.x = (r.x - mu) * rs * g.x + be.x;
        o.y = (r.y - mu) * rs * g.y + be.y;
        o.z = (r.z - mu) * rs * g.z + be.z;
        o.w = (r.w - mu) * rs * g.w + be.w;
        *(float4*)(fmS + c * 128 + y4) = o;
      }
      __syncthreads();
      {                                         // transpose + 3-way bf16 split
        const int ty = t & 127, cg = t >> 7;
        unsigned int d0[4], d1[4], d2[4];
        #pragma unroll
        for (int jj = 0; jj < 4; ++jj) {
          unsigned int h[2], m[2], l[2];
          #pragma unroll
          for (int e = 0; e < 2; ++e) {
            float v = fmS[(cg * 8 + jj * 2 + e) * 128 + ty];
            unsigned int u = __float_as_uint(v);
            float r1 = v - __uint_as_float(u & 0xffff0000u);
            unsigned int u1 = __float_as_uint(r1);
            float r2 = r1 - __uint_as_float(u1 & 0xffff0000u);
            h[e] = u >> 16; m[e] = u1 >> 16; l[e] = __float_as_uint(r2) >> 16;
          }
          d0[jj] = h[0] | (h[1] << 16);
          d1[jj] = m[0] | (m[1] << 16);
          d2[jj] = l[0] | (l[1] << 16);
        }
        float* pp = pls + ty * 20 + cg * 4;
        *reinterpret_cast<uint4*>(pp)        = make_uint4(d0[0], d0[1], d0[2], d0[3]);
        *reinterpret_cast<uint4*>(pp + 2560) = make_uint4(d1[0], d1[1], d1[2], d1[3]);
        *reinterpret_cast<uint4*>(pp + 5120) = make_uint4(d2[0], d2[1], d2[2], d2[3]);
      }
      __syncthreads();
      #pragma unroll
      for (int yt = 0; yt < 4; ++yt) {
        const float* bp = pls + ((yc * 4 + yt) * 16 + ln) * 20 + kb * 4;
        bf16x8 B0 = *(const bf16x8*)(bp);
        bf16x8 B1 = *(const bf16x8*)(bp + 2560);
        bf16x8 B2 = *(const bf16x8*)(bp + 5120);
        #pragma unroll
        for (int ot = 0; ot < 2; ++ot) {
          f32x4 c = qacc[ot][yt];
          c = __builtin_amdgcn_mfma_f32_16x16x32_bf16(af[ot][0], B0, c, 0, 0, 0);
          c = __builtin_amdgcn_mfma_f32_16x16x32_bf16(af[ot][0], B1, c, 0, 0, 0);
          c = __builtin_amdgcn_mfma_f32_16x16x32_bf16(af[ot][1], B0, c, 0, 0, 0);
          c = __builtin_amdgcn_mfma_f32_16x16x32_bf16(af[ot][0], B2, c, 0, 0, 0);
          c = __builtin_amdgcn_mfma_f32_16x16x32_bf16(af[ot][1], B1, c, 0, 0, 0);
          c = __builtin_amdgcn_mfma_f32_16x16x32_bf16(af[ot][2], B0, c, 0, 0, 0);
          qacc[ot][yt] = c;
        }
      }
    }

    for (int hh = 0; hh < 4; ++hh) {            // head = qblk*4 + hh
      // waves owning this head write q transposed into qh[d][y] (acc layout, m89 map)
      if (or2 == hh) {
        #pragma unroll
        for (int ot = 0; ot < 2; ++ot)
          #pragma unroll
          for (int yt = 0; yt < 4; ++yt) {
            f32x4 a = qacc[ot][yt];
            int yb = (yc * 4 + yt) * 16 + ln;
            #pragma unroll
            for (int r = 0; r < 4; ++r)
              qh[(ot * 16 + kb * 4 + r) * 132 + yb] = a[r];
          }
      }
      if (t < 256)
        *(float4*)(ctxS + t * 4) =
            *(const float4*)(ws + OFF_CTXS + (size_t)(b * 8 + qblk * 4 + hh) * 1024 + t * 4);
      __syncthreads();                          // S2: qh/ctxS visible; prior pls readers done
      // softmax over d (no max-shift needed: |q| small) + q@ctx; e split 4 ways
      float ge[8];
      #pragma unroll
      for (int i = 0; i < 8; ++i) ge[i] = 0.0f;
      float ssum = 0.0f;
      #pragma unroll 4
      for (int dd = 0; dd < 32; ++dd) {
        float p = __expf(qh[dd * 132 + yq]);
        ssum += p;
        const float4 c0 = *(const float4*)(ctxS + dd * 32 + eg * 8);
        const float4 c1 = *(const float4*)(ctxS + dd * 32 + eg * 8 + 4);
        ge[0] = fmaf(p, c0.x, ge[0]); ge[1] = fmaf(p, c0.y, ge[1]);
        ge[2] = fmaf(p, c0.z, ge[2]); ge[3] = fmaf(p, c0.w, ge[3]);
        ge[4] = fmaf(p, c1.x, ge[4]); ge[5] = fmaf(p, c1.y, ge[5]);
        ge[6] = fmaf(p, c1.z, ge[6]); ge[7] = fmaf(p, c1.w, ge[7]);
      }
      const float rinv = 1.0f / ssum;
      // gelu + 3-way bf16 split -> gel planes (pls region; cp = eg*8+i at y = yq)
      {
        unsigned int d0[4], d1[4], d2[4];
        #pragma unroll
        for (int j = 0; j < 4; ++j) {
          unsigned int hbt[2], mbt[2], lbt[2];
          #pragma unroll
          for (int e = 0; e < 2; ++e) {
            float v = ge[2 * j + e] * rinv;
            v = 0.5f * v * (1.0f + erff(v * 0.70710678118654752f));
            unsigned int u = __float_as_uint(v);
            float r1 = v - __uint_as_float(u & 0xffff0000u);
            unsigned int u1 = __float_as_uint(r1);
            float r2 = r1 - __uint_as_float(u1 & 0xffff0000u);
            hbt[e] = u >> 16; mbt[e] = u1 >> 16; lbt[e] = __float_as_uint(r2) >> 16;
          }
          d0[j] = hbt[0] | (hbt[1] << 16);
          d1[j] = mbt[0] | (mbt[1] << 16);
          d2[j] = lbt[0] | (lbt[1] << 16);
        }
        float* pp = pls + yq * 20 + eg * 4;
        *reinterpret_cast<uint4*>(pp)        = make_uint4(d0[0], d0[1], d0[2], d0[3]);
        *reinterpret_cast<uint4*>(pp + 2560) = make_uint4(d1[0], d1[1], d1[2], d1[3]);
        *reinterpret_cast<uint4*>(pp + 5120) = make_uint4(d2[0], d2[1], d2[2], d2[3]);
      }
      __syncthreads();                          // S3: gel planes visible
      // out-conv MFMA: oacc[o][y] += wout[o][cp] * gel[cp][y], K=32 (this head's cp)
      bf16x8 oaf[2][3];
      #pragma unroll
      for (int ot = 0; ot < 2; ++ot)
        #pragma unroll
        for (int p = 0; p < 3; ++p)
          oaf[ot][p] = *(const bf16x8*)(wospl + p * 32768 +
              ((or2 * 32 + ot * 16 + ln) * 256 + (qblk * 4 + hh) * 32 + kb * 8));
      #pragma unroll
      for (int yt = 0; yt < 4; ++yt) {
        const float* bp = pls + ((yc * 4 + yt) * 16 + ln) * 20 + kb * 4;
        bf16x8 B0 = *(const bf16x8*)(bp);
        bf16x8 B1 = *(const bf16x8*)(bp + 2560);
        bf16x8 B2 = *(const bf16x8*)(bp + 5120);
        #pragma unroll
        for (int ot = 0; ot < 2; ++ot) {
          f32x4 c = oacc[ot][yt];
          c = __builtin_amdgcn_mfma_f32_16x16x32_bf16(oaf[ot][0], B0, c, 0, 0, 0);
          c = __builtin_amdgcn_mfma_f32_16x16x32_bf16(oaf[ot][0], B1, c, 0, 0, 0);
          c = __builtin_amdgcn_mfma_f32_16x16x32_bf16(oaf[ot][1], B0, c, 0, 0, 0);
          c = __builtin_amdgcn_mfma_f32_16x16x32_bf16(oaf[ot][0], B2, c, 0, 0, 0);
          c = __builtin_amdgcn_mfma_f32_16x16x32_bf16(oaf[ot][1], B1, c, 0, 0, 0);
          c = __builtin_amdgcn_mfma_f32_16x16x32_bf16(oaf[ot][2], B0, c, 0, 0, 0);
          oacc[ot][yt] = c;
        }
      }
    }
  }

  // ---- LN1 over y per o-row (acc layout: o = or2*32+ot*16+kb*4+r, y = (yc*4+yt)*16+ln) ----
  __syncthreads();
  float* red_s = sm;          // aliases fmS
  float* red_q = sm + 4096;   // aliases pls
  #pragma unroll
  for (int ot = 0; ot < 2; ++ot)
    #pragma unroll
    for (int r = 0; r < 4; ++r) {
      int o = or2 * 32 + ot * 16 + kb * 4 + r;
      float s = 0.0f, q = 0.0f;
      #pragma unroll
      for (int yt = 0; yt < 4; ++yt) { float v = oacc[ot][yt][r]; s += v; q = fmaf(v, v, q); }
      red_s[o * 32 + yc * 16 + ln] = s;
      red_q[o * 32 + yc * 16 + ln] = q;
    }
  __syncthreads();
  if (t < 128) {
    double s = 0.0, q = 0.0;
    #pragma unroll
    for (int i = 0; i < 32; ++i) { s += red_s[t * 32 + i]; q += red_q[t * 32 + i]; }
    double mu = s * (1.0 / 128.0);
    double var = q * (1.0 / 128.0) - mu * mu;
    lnm[t] = (float)mu;
    lnr[t] = (float)(1.0 / sqrt(var + 1e-5));
  }
  __syncthreads();
  float g1v[4], b1v[4];
  #pragma unroll
  for (int yt = 0; yt < 4; ++yt) {
    int y = (yc * 4 + yt) * 16 + ln;
    g1v[yt] = g1[y]; b1v[yt] = b1[y];
  }
  #pragma unroll
  for (int ot = 0; ot < 2; ++ot)
    #pragma unroll
    for (int r = 0; r < 4; ++r) {
      int o = or2 * 32 + ot * 16 + kb * 4 + r;
      float mu = lnm[o], rs = lnr[o];
      #pragma unroll
      for (int yt = 0; yt < 4; ++yt) {
        int y = (yc * 4 + yt) * 16 + ln;
        out[(((size_t)(b * 128 + o)) * 128 + x) * 128 + y] =
            (oacc[ot][yt][r] - mu) * rs * g1v[yt] + b1v[yt];
      }
    }
}

extern "C" void kernel_launch(void* const* d_in, const int* in_sizes, int n_in,
                              void* d_out, int out_size, void* d_ws, size_t ws_size,
                              hipStream_t stream) {
  const float* fmap = (const float*)d_in[0];
  const float* g0   = (const float*)d_in[1];
  const float* b0   = (const float*)d_in[2];
  const float* wqkv = (const float*)d_in[3];
  const float* wout = (const float*)d_in[4];
  const float* g1   = (const float*)d_in[5];
  const float* b1   = (const float*)d_in[6];
  float* ws  = (float*)d_ws;
  float* out = (float*)d_out;

  hipMemsetAsync((char*)d_ws + (size_t)OFF_CTXA * 4, 0, (size_t)2162688 * 4, stream);
  prep_kernel<<<512, 256, 0, stream>>>(wqkv, wout, ws);
  ln0_stats_kernel<<<65536, 256, 0, stream>>>(fmap, ws);
  kv_ctx_kernel<<<dim3(128, 16), 512, 0, stream>>>(fmap, g0, b0, ws);
  ctx_reduce_kernel<<<128, 256, 0, stream>>>(ws);
  final_kernel<<<dim3(128, 16), 512, 0, stream>>>(fmap, g0, b0, g1, b1, ws, out);
}

// Round 3
// 1043.469 us; speedup vs baseline: 1.2929x; 1.0111x over previous
//
#include <hip/hip_runtime.h>
#include <math.h>

// B=16, C=128, X=128, Y=128, heads=8, dh=32, inner=256
// ws layout (float offsets):
#define OFF_MU    0u          // [262144] per (b,c,x)
#define OFF_RSTD  262144u
#define OFF_CTXA  524288u     // [bh=128][xg=16][1056] atomic partials (U 1024 + sexp 32)
#define OFF_CTXP  2686976u    // sigma-permuted ctx: [bh=128][3 planes][32 e][32 k] bf16 (3072 shorts/bh)
#define OFF_WSPL  2883584u    // 3 bf16 planes of permuted k/v weights (65536 shorts/plane)
#define OFF_WQSPL 2981888u    // 3 bf16 planes of q weights [256 o][128 c] (32768 shorts/plane)
#define OFF_WOSPL 3031040u    // 3 bf16 planes of wout [128 o][256 k-sigma] (32768 shorts/plane)
                              // end: 3080192 floats = 12.32 MB

typedef __attribute__((ext_vector_type(8))) short bf16x8;
typedef __attribute__((ext_vector_type(4))) float f32x4;

__device__ __forceinline__ void split3(float v, unsigned& h, unsigned& m, unsigned& l) {
  unsigned u = __float_as_uint(v);
  float r1 = v - __uint_as_float(u & 0xffff0000u);
  unsigned u1 = __float_as_uint(r1);
  float r2 = r1 - __uint_as_float(u1 & 0xffff0000u);
  h = u >> 16; m = u1 >> 16; l = __float_as_uint(r2) >> 16;
}

// 6-product split-bf16 MFMA: A,B are 3-plane splits (h,m,l)
__device__ __forceinline__ f32x4 mfma6(const bf16x8& A0, const bf16x8& A1, const bf16x8& A2,
                                       const bf16x8& B0, const bf16x8& B1, const bf16x8& B2,
                                       f32x4 c) {
  c = __builtin_amdgcn_mfma_f32_16x16x32_bf16(A0, B0, c, 0, 0, 0);
  c = __builtin_amdgcn_mfma_f32_16x16x32_bf16(A0, B1, c, 0, 0, 0);
  c = __builtin_amdgcn_mfma_f32_16x16x32_bf16(A1, B0, c, 0, 0, 0);
  c = __builtin_amdgcn_mfma_f32_16x16x32_bf16(A0, B2, c, 0, 0, 0);
  c = __builtin_amdgcn_mfma_f32_16x16x32_bf16(A1, B1, c, 0, 0, 0);
  c = __builtin_amdgcn_mfma_f32_16x16x32_bf16(A2, B0, c, 0, 0, 0);
  return c;
}

// ---------------- prep: bf16 3-way weight splits ----------------
__global__ void prep_kernel(const float* __restrict__ wqkv,
                            const float* __restrict__ wout,
                            float* __restrict__ ws) {
  int idx = blockIdx.x * 256 + threadIdx.x;   // 512 blocks -> 131072
  float v;
  unsigned short* wp;
  unsigned plane, slot;
  if (idx < 65536) {
    // k/v weight rows, permuted per-blk
    int row = idx >> 7, c = idx & 127;   // row 0..511
    int blk = row >> 7, ol = row & 127;
    int hh = (ol >> 5) & 1;
    int src = ((ol & 64) ? 512 : 256) + (2 * blk + hh) * 32 + (ol & 31);
    v = wqkv[src * 128 + c];
    wp = (unsigned short*)(ws + OFF_WSPL);
    plane = 65536; slot = (unsigned)idx;
  } else if (idx < 98304) {
    // q weights: rows o=0..255 of wqkv, layout [o][c]
    int j = idx - 65536;
    v = wqkv[j];
    wp = (unsigned short*)(ws + OFF_WQSPL);
    plane = 32768; slot = (unsigned)j;
  } else {
    // wout sigma-permuted: dst slot [o][k], src cp within each 32-chunk:
    // k = kb*8+ot*4+r  <->  cp = ot*16+kb*4+r
    int j = idx - 98304;
    int o = j >> 8, k = j & 255;
    int cp = (k & 0xE0) | (((k >> 2) & 1) << 4) | (((k >> 3) & 3) << 2) | (k & 3);
    v = wout[o * 256 + cp];
    wp = (unsigned short*)(ws + OFF_WOSPL);
    plane = 32768; slot = (unsigned)j;
  }
  unsigned h, m, l;
  split3(v, h, m, l);
  wp[slot]             = (unsigned short)h;
  wp[plane + slot]     = (unsigned short)m;
  wp[2 * plane + slot] = (unsigned short)l;
}

// ---------------- LN0 stats per (b,c,x) row over y ----------------
__global__ void ln0_stats_kernel(const float* __restrict__ fmap,
                                 float* __restrict__ ws) {
  const int wid = threadIdx.x >> 6, lane = threadIdx.x & 63;
  const int row = blockIdx.x * 4 + wid;       // < 262144
  const float* p = fmap + (size_t)row * 128;
  float a0 = p[lane], a1 = p[lane + 64];
  double s = (double)a0 + (double)a1;
  double q = (double)a0 * a0 + (double)a1 * a1;
  #pragma unroll
  for (int off = 32; off; off >>= 1) {
    s += __shfl_xor(s, off);
    q += __shfl_xor(q, off);
  }
  if (lane == 0) {
    double mu = s * (1.0 / 128.0);
    double var = q * (1.0 / 128.0) - mu * mu;
    ws[OFF_MU + row] = (float)mu;
    ws[OFF_RSTD + row] = (float)(1.0 / sqrt(var + 1e-5));
  }
}

// ---------------- K1: all-heads K/V + context partials, one block per (b,x) ----------------
// (unchanged from round 2)
__launch_bounds__(512, 4)
__global__ void kv_ctx_kernel(const float* __restrict__ fmap,
                              const float* __restrict__ g0,
                              const float* __restrict__ b0,
                              float* __restrict__ ws) {
  __shared__ float sm[13888];
  const int x = blockIdx.x, b = blockIdx.y, t = threadIdx.x;
  const int wave = t >> 6, lane = t & 63;
  const int ln = lane & 15, kb = lane >> 4;
  const int or2 = wave >> 1, yc = wave & 1;
  const int dt = lane >> 3, et = lane & 7;
  const int xg = x >> 3;

  float* pb  = sm;            // [64][36]
  float* vb  = sm + 2304;     // [64][36]
  float* vss = sm + 4608;     // [4][64]
  float* ser = sm + 4864;     // [8][8][4]
  float* rnS = sm + 5120;     // [64]
  float* red = sm + 5184;     // [512][16] (aliases planes)
  float* pls = sm + 5184;     // 3 planes x [128 y][20 dw]
  float* muS = sm + 13376;
  float* rsS = sm + 13504;
  float* g0S = sm + 13632;
  float* b0S = sm + 13760;
  float* fmS = sm;            // [32][128] (aliases pb/vb)

  if (t < 128) {
    muS[t] = ws[OFF_MU + (unsigned)((b * 128 + t) * 128 + x)];
    rsS[t] = ws[OFF_RSTD + (unsigned)((b * 128 + t) * 128 + x)];
  } else if (t < 256) g0S[t - 128] = g0[t - 128];
  else if (t < 384) b0S[t - 256] = b0[t - 256];

  const unsigned short* wspl = (const unsigned short*)(ws + OFF_WSPL);

  for (int blk = 0; blk < 4; ++blk) {
    f32x4 acc[2][4];
    #pragma unroll
    for (int i = 0; i < 2; ++i)
      #pragma unroll
      for (int j = 0; j < 4; ++j) acc[i][j] = (f32x4){0.f, 0.f, 0.f, 0.f};

    for (int cc = 0; cc < 4; ++cc) {
      bf16x8 af[2][3];
      #pragma unroll
      for (int ot = 0; ot < 2; ++ot)
        #pragma unroll
        for (int p = 0; p < 3; ++p)
          af[ot][p] = *(const bf16x8*)(wspl + p * 65536 +
              ((blk * 128 + or2 * 32 + ot * 16 + ln) * 128 + cc * 32 + kb * 8));

      __syncthreads();
      #pragma unroll
      for (int it = 0; it < 2; ++it) {
        int idx4 = it * 512 + t;
        int c = idx4 >> 5, y4 = (idx4 & 31) * 4;
        int cg = cc * 32 + c;
        const float4 r = *(const float4*)(fmap + (((size_t)(b * 128 + cg)) * 128 + x) * 128 + y4);
        float mu = muS[cg], rs = rsS[cg];
        float4 g = *(const float4*)(g0S + y4);
        float4 be = *(const float4*)(b0S + y4);
        float4 o;
        o.x = (r.x - mu) * rs * g.x + be.x;
        o.y = (r.y - mu) * rs * g.y + be.y;
        o.z = (r.z - mu) * rs * g.z + be.z;
        o.w = (r.w - mu) * rs * g.w + be.w;
        *(float4*)(fmS + c * 128 + y4) = o;
      }
      __syncthreads();
      {                                         // transpose + 3-way bf16 split
        const int ty = t & 127, cg = t >> 7;
        unsigned int d0[4], d1[4], d2[4];
        #pragma unroll
        for (int jj = 0; jj < 4; ++jj) {
          unsigned int h[2], m[2], l[2];
          #pragma unroll
          for (int e = 0; e < 2; ++e) {
            float v = fmS[(cg * 8 + jj * 2 + e) * 128 + ty];
            split3(v, h[e], m[e], l[e]);
          }
          d0[jj] = h[0] | (h[1] << 16);
          d1[jj] = m[0] | (m[1] << 16);
          d2[jj] = l[0] | (l[1] << 16);
        }
        float* pp = pls + ty * 20 + cg * 4;
        *reinterpret_cast<uint4*>(pp)        = make_uint4(d0[0], d0[1], d0[2], d0[3]);
        *reinterpret_cast<uint4*>(pp + 2560) = make_uint4(d1[0], d1[1], d1[2], d1[3]);
        *reinterpret_cast<uint4*>(pp + 5120) = make_uint4(d2[0], d2[1], d2[2], d2[3]);
      }
      __syncthreads();
      #pragma unroll
      for (int yt = 0; yt < 4; ++yt) {
        const float* bp = pls + ((yc * 4 + yt) * 16 + ln) * 20 + kb * 4;
        bf16x8 B0 = *(const bf16x8*)(bp);
        bf16x8 B1 = *(const bf16x8*)(bp + 2560);
        bf16x8 B2 = *(const bf16x8*)(bp + 5120);
        #pragma unroll
        for (int ot = 0; ot < 2; ++ot)
          acc[ot][yt] = mfma6(af[ot][0], af[ot][1], af[ot][2], B0, B1, B2, acc[ot][yt]);
      }
    }

    for (int hh = 0; hh < 2; ++hh) {
      float u[16], se[4];
      #pragma unroll
      for (int i = 0; i < 16; ++i) u[i] = 0.0f;
      se[0] = se[1] = se[2] = se[3] = 0.0f;

      for (int hf = 0; hf < 2; ++hf) {
        if (wave == hh * 2 + hf) {
          #pragma unroll
          for (int ot = 0; ot < 2; ++ot)
            #pragma unroll
            for (int yt = 0; yt < 4; ++yt) {
              f32x4 a = acc[ot][yt];
              float4 p;
              p.x = __expf(a[0]); p.y = __expf(a[1]);
              p.z = __expf(a[2]); p.w = __expf(a[3]);
              *(float4*)(pb + (yt * 16 + ln) * 36 + ot * 16 + kb * 4) = p;
            }
        }
        if (wave == 4 + hh * 2 + hf) {
          #pragma unroll
          for (int yt = 0; yt < 4; ++yt) {
            f32x4 a0 = acc[0][yt], a1 = acc[1][yt];
            int yl = yt * 16 + ln;
            *(float4*)(vb + yl * 36 + kb * 4)      = make_float4(a0[0], a0[1], a0[2], a0[3]);
            *(float4*)(vb + yl * 36 + 16 + kb * 4) = make_float4(a1[0], a1[1], a1[2], a1[3]);
            float s = a0[0] * a0[0] + a0[1] * a0[1] + a0[2] * a0[2] + a0[3] * a0[3]
                    + a1[0] * a1[0] + a1[1] * a1[1] + a1[2] * a1[2] + a1[3] * a1[3];
            vss[kb * 64 + yl] = s;
          }
        }
        __syncthreads();
        if (t < 64) {
          float s2 = vss[t] + vss[64 + t] + vss[128 + t] + vss[192 + t];
          rnS[t] = 1.0f / fmaxf(sqrtf(s2), 1e-12f);
        }
        __syncthreads();
        #pragma unroll 2
        for (int yy = 0; yy < 8; ++yy) {
          int y = wave * 8 + yy;
          const float4 p = *(const float4*)(pb + y * 36 + dt * 4);
          float4 v = *(const float4*)(vb + y * 36 + et * 4);
          float rn = rnS[y];
          v.x *= rn; v.y *= rn; v.z *= rn; v.w *= rn;
          se[0] += p.x; se[1] += p.y; se[2] += p.z; se[3] += p.w;
          u[0]  = fmaf(p.x, v.x, u[0]);  u[1]  = fmaf(p.x, v.y, u[1]);
          u[2]  = fmaf(p.x, v.z, u[2]);  u[3]  = fmaf(p.x, v.w, u[3]);
          u[4]  = fmaf(p.y, v.x, u[4]);  u[5]  = fmaf(p.y, v.y, u[5]);
          u[6]  = fmaf(p.y, v.z, u[6]);  u[7]  = fmaf(p.y, v.w, u[7]);
          u[8]  = fmaf(p.z, v.x, u[8]);  u[9]  = fmaf(p.z, v.y, u[9]);
          u[10] = fmaf(p.z, v.z, u[10]); u[11] = fmaf(p.z, v.w, u[11]);
          u[12] = fmaf(p.w, v.x, u[12]); u[13] = fmaf(p.w, v.y, u[13]);
          u[14] = fmaf(p.w, v.z, u[14]); u[15] = fmaf(p.w, v.w, u[15]);
        }
        __syncthreads();
      }
      *(float4*)(red + t * 16 + 0)  = make_float4(u[0], u[1], u[2], u[3]);
      *(float4*)(red + t * 16 + 4)  = make_float4(u[4], u[5], u[6], u[7]);
      *(float4*)(red + t * 16 + 8)  = make_float4(u[8], u[9], u[10], u[11]);
      *(float4*)(red + t * 16 + 12) = make_float4(u[12], u[13], u[14], u[15]);
      if (et == 0)
        *(float4*)(ser + (wave * 8 + dt) * 4) = make_float4(se[0], se[1], se[2], se[3]);
      __syncthreads();
      {
        const int tile = t >> 3;
        const int i0 = (t & 7) * 2;
        float s0 = 0.0f, s1 = 0.0f;
        #pragma unroll
        for (int w = 0; w < 8; ++w) {
          s0 += red[(w * 64 + tile) * 16 + i0];
          s1 += red[(w * 64 + tile) * 16 + i0 + 1];
        }
        const int d = (tile >> 3) * 4 + (i0 >> 2);
        const int e = (tile & 7) * 4 + (i0 & 3);
        float* ca = ws + OFF_CTXA + ((size_t)(b * 8 + blk * 2 + hh) * 16 + xg) * 1056;
        atomicAdd(ca + d * 32 + e, s0);
        atomicAdd(ca + d * 32 + e + 1, s1);
        if (t < 32) {
          float ss = 0.0f;
          #pragma unroll
          for (int w = 0; w < 8; ++w) ss += ser[(w * 8 + (t >> 2)) * 4 + (t & 3)];
          atomicAdd(ca + 1024 + t, ss);
        }
      }
    }
  }
}

// ---------------- reduce x-group partials, fold scales, emit sigma-permuted bf16 planes ----------------
__global__ void ctx_reduce_kernel(float* __restrict__ ws) {
  __shared__ float sume[32];
  const int bh = blockIdx.x, t = threadIdx.x;
  const float* ca = ws + OFF_CTXA + (size_t)bh * 16 * 1056;
  if (t < 32) {
    double a = 0.0;
    #pragma unroll
    for (int xg = 0; xg < 16; ++xg) a += ca[xg * 1056 + 1024 + t];
    sume[t] = (float)a;
  }
  __syncthreads();
  const double sb = (1.0 / 16384.0) * 0.17677669529663688;  // inv^2 * dh^-0.5
  unsigned short* cp = (unsigned short*)(ws + OFF_CTXP) + (size_t)bh * 3072;
  #pragma unroll
  for (int i = 0; i < 4; ++i) {
    int de = t + 256 * i;
    int d = de >> 5, e = de & 31;
    double a = 0.0;
    #pragma unroll
    for (int xg = 0; xg < 16; ++xg) a += ca[xg * 1056 + de];
    float v = (float)(a * sb / (double)sume[d]);
    // sigma: k = kb*8 + ot*4 + r with d = ot*16 + kb*4 + r
    int k = ((d >> 2) & 3) * 8 + ((d >> 4) & 1) * 4 + (d & 3);
    unsigned h, m, l;
    split3(v, h, m, l);
    cp[e * 32 + k]        = (unsigned short)h;
    cp[1024 + e * 32 + k] = (unsigned short)m;
    cp[2048 + e * 32 + k] = (unsigned short)l;
  }
}

// ---------------- final v3: Q-MFMA -> in-reg softmax -> ctx-MFMA -> in-reg gelu -> out-conv MFMA -> LN1 ----------------
// LDS floats: staging fmS[32][128]@0 + pls 3x[128][20]@4096 (11776); gel planes 3x[128][36]@0
// (13824, alias staging); muS@13824,rsS,g0S,b0S, lnm@14336, lnr@14464 -> 14592 floats = 58.4 KB
__launch_bounds__(512, 4)
__global__ void final_kernel(const float* __restrict__ fmap,
                             const float* __restrict__ g0,
                             const float* __restrict__ b0,
                             const float* __restrict__ g1,
                             const float* __restrict__ b1,
                             const float* __restrict__ ws,
                             float* __restrict__ out) {
  __shared__ float sm[14592];
  const int x = blockIdx.x, b = blockIdx.y, t = threadIdx.x;
  const int wave = t >> 6, lane = t & 63;
  const int ln = lane & 15, kb = lane >> 4;   // MFMA fragment coords
  const int or2 = wave >> 1, yc = wave & 1;   // wave tile: o-tiles(or head) x y-halves

  float* fmS = sm;            // [32][128] staging
  float* pls = sm + 4096;     // 3 planes x [128][20] staging splits
  float* gel = sm;            // 3 planes x [128][36] gel splits (aliases staging)
  float* muS = sm + 13824;
  float* rsS = sm + 13952;
  float* g0S = sm + 14080;
  float* b0S = sm + 14208;
  float* lnm = sm + 14336;
  float* lnr = sm + 14464;

  if (t < 128) {
    muS[t] = ws[OFF_MU + (unsigned)((b * 128 + t) * 128 + x)];
    rsS[t] = ws[OFF_RSTD + (unsigned)((b * 128 + t) * 128 + x)];
  } else if (t < 256) g0S[t - 128] = g0[t - 128];
  else if (t < 384) b0S[t - 256] = b0[t - 256];

  const unsigned short* wqspl = (const unsigned short*)(ws + OFF_WQSPL);
  const unsigned short* wospl = (const unsigned short*)(ws + OFF_WOSPL);
  const unsigned short* ctxp  = (const unsigned short*)(ws + OFF_CTXP);

  f32x4 oacc[2][4];
  #pragma unroll
  for (int i = 0; i < 2; ++i)
    #pragma unroll
    for (int j = 0; j < 4; ++j) oacc[i][j] = (f32x4){0.f, 0.f, 0.f, 0.f};

  for (int qblk = 0; qblk < 2; ++qblk) {
    f32x4 qacc[2][4];
    #pragma unroll
    for (int i = 0; i < 2; ++i)
      #pragma unroll
      for (int j = 0; j < 4; ++j) qacc[i][j] = (f32x4){0.f, 0.f, 0.f, 0.f};

    // ---- Q matmul over 4 c-chunks ----
    for (int cc = 0; cc < 4; ++cc) {
      bf16x8 af[2][3];
      #pragma unroll
      for (int ot = 0; ot < 2; ++ot)
        #pragma unroll
        for (int p = 0; p < 3; ++p)
          af[ot][p] = *(const bf16x8*)(wqspl + p * 32768 +
              ((qblk * 128 + or2 * 32 + ot * 16 + ln) * 128 + cc * 32 + kb * 8));

      __syncthreads();                          // staging region free of prior readers
      #pragma unroll
      for (int it = 0; it < 2; ++it) {          // stage fm chunk, LN0 applied (f32)
        int idx4 = it * 512 + t;
        int c = idx4 >> 5, y4 = (idx4 & 31) * 4;
        int cg = cc * 32 + c;
        const float4 r = *(const float4*)(fmap + (((size_t)(b * 128 + cg)) * 128 + x) * 128 + y4);
        float mu = muS[cg], rs = rsS[cg];
        float4 g = *(const float4*)(g0S + y4);
        float4 be = *(const float4*)(b0S + y4);
        float4 o;
        o.x = (r.x - mu) * rs * g.x + be.x;
        o.y = (r.y - mu) * rs * g.y + be.y;
        o.z = (r.z - mu) * rs * g.z + be.z;
        o.w = (r.w - mu) * rs * g.w + be.w;
        *(float4*)(fmS + c * 128 + y4) = o;
      }
      __syncthreads();
      {                                         // transpose + 3-way bf16 split
        const int ty = t & 127, cg = t >> 7;
        unsigned int d0[4], d1[4], d2[4];
        #pragma unroll
        for (int jj = 0; jj < 4; ++jj) {
          unsigned int h[2], m[2], l[2];
          #pragma unroll
          for (int e = 0; e < 2; ++e) {
            float v = fmS[(cg * 8 + jj * 2 + e) * 128 + ty];
            split3(v, h[e], m[e], l[e]);
          }
          d0[jj] = h[0] | (h[1] << 16);
          d1[jj] = m[0] | (m[1] << 16);
          d2[jj] = l[0] | (l[1] << 16);
        }
        float* pp = pls + ty * 20 + cg * 4;
        *reinterpret_cast<uint4*>(pp)        = make_uint4(d0[0], d0[1], d0[2], d0[3]);
        *reinterpret_cast<uint4*>(pp + 2560) = make_uint4(d1[0], d1[1], d1[2], d1[3]);
        *reinterpret_cast<uint4*>(pp + 5120) = make_uint4(d2[0], d2[1], d2[2], d2[3]);
      }
      __syncthreads();
      #pragma unroll
      for (int yt = 0; yt < 4; ++yt) {
        const float* bp = pls + ((yc * 4 + yt) * 16 + ln) * 20 + kb * 4;
        bf16x8 B0 = *(const bf16x8*)(bp);
        bf16x8 B1 = *(const bf16x8*)(bp + 2560);
        bf16x8 B2 = *(const bf16x8*)(bp + 5120);
        #pragma unroll
        for (int ot = 0; ot < 2; ++ot)
          qacc[ot][yt] = mfma6(af[ot][0], af[ot][1], af[ot][2], B0, B1, B2, qacc[ot][yt]);
      }
    }

    // ---- in-register exp + ssum (4-lane butterfly) + 3-split pack (sigma layout) ----
    // lane holds d = ot*16+kb*4+r at y = (yc*4+yt)*16+ln; B-frag k = kb*8+ot*4+r == own values
    float rssum[4];
    bf16x8 pf0[4], pf1[4], pf2[4];
    #pragma unroll
    for (int yt = 0; yt < 4; ++yt) {
      float pv[8];
      #pragma unroll
      for (int ot = 0; ot < 2; ++ot)
        #pragma unroll
        for (int r = 0; r < 4; ++r)
          pv[ot * 4 + r] = __expf(qacc[ot][yt][r]);
      float ps = ((pv[0] + pv[1]) + (pv[2] + pv[3])) + ((pv[4] + pv[5]) + (pv[6] + pv[7]));
      ps += __shfl_xor(ps, 16);
      ps += __shfl_xor(ps, 32);
      rssum[yt] = 1.0f / ps;
      unsigned wh[4], wm[4], wl[4];
      #pragma unroll
      for (int j = 0; j < 4; ++j) {
        unsigned h0, m0, l0, h1, m1, l1;
        split3(pv[2 * j], h0, m0, l0);
        split3(pv[2 * j + 1], h1, m1, l1);
        wh[j] = h0 | (h1 << 16);
        wm[j] = m0 | (m1 << 16);
        wl[j] = l0 | (l1 << 16);
      }
      uint4 uh = make_uint4(wh[0], wh[1], wh[2], wh[3]);
      uint4 um = make_uint4(wm[0], wm[1], wm[2], wm[3]);
      uint4 ul = make_uint4(wl[0], wl[1], wl[2], wl[3]);
      pf0[yt] = *(const bf16x8*)&uh;
      pf1[yt] = *(const bf16x8*)&um;
      pf2[yt] = *(const bf16x8*)&ul;
    }

    // ---- ge[e][y] = sum_d ctx[d][e] * exp(q[d][y]) via MFMA (A from L2, B in-reg) ----
    f32x4 ge[2][4];
    const unsigned short* chp = ctxp + (size_t)(b * 8 + qblk * 4 + or2) * 3072;
    #pragma unroll
    for (int ot = 0; ot < 2; ++ot) {
      bf16x8 aq0 = *(const bf16x8*)(chp +        (ot * 16 + ln) * 32 + kb * 8);
      bf16x8 aq1 = *(const bf16x8*)(chp + 1024 + (ot * 16 + ln) * 32 + kb * 8);
      bf16x8 aq2 = *(const bf16x8*)(chp + 2048 + (ot * 16 + ln) * 32 + kb * 8);
      #pragma unroll
      for (int yt = 0; yt < 4; ++yt) {
        f32x4 c = (f32x4){0.f, 0.f, 0.f, 0.f};
        ge[ot][yt] = mfma6(aq0, aq1, aq2, pf0[yt], pf1[yt], pf2[yt], c);
      }
    }

    // ---- gelu in-register (ge layout: e = ot*16+kb*4+r, y = (yc*4+yt)*16+ln) ----
    #pragma unroll
    for (int ot = 0; ot < 2; ++ot)
      #pragma unroll
      for (int yt = 0; yt < 4; ++yt)
        #pragma unroll
        for (int r = 0; r < 4; ++r) {
          float v = ge[ot][yt][r] * rssum[yt];
          ge[ot][yt][r] = 0.5f * v * (1.0f + erff(v * 0.70710678118654752f));
        }

    // ---- out-conv in 2 phases of K=64 (heads {2ph, 2ph+1}) ----
    for (int ph = 0; ph < 2; ++ph) {
      __syncthreads();                          // prior readers of gel region done
      if ((or2 >> 1) == ph) {                   // this wave's head is in the chunk
        const int c16 = (or2 & 1) * 16;
        #pragma unroll
        for (int yt = 0; yt < 4; ++yt) {
          float* grow = gel + ((yc * 4 + yt) * 16 + ln) * 36 + c16 + kb * 4;
          #pragma unroll
          for (int ot = 0; ot < 2; ++ot) {
            unsigned h0, m0, l0, h1, m1, l1, h2, m2, l2, h3, m3, l3;
            split3(ge[ot][yt][0], h0, m0, l0);
            split3(ge[ot][yt][1], h1, m1, l1);
            split3(ge[ot][yt][2], h2, m2, l2);
            split3(ge[ot][yt][3], h3, m3, l3);
            *(uint2*)(grow + ot * 2)        = make_uint2(h0 | (h1 << 16), h2 | (h3 << 16));
            *(uint2*)(grow + 4608 + ot * 2) = make_uint2(m0 | (m1 << 16), m2 | (m3 << 16));
            *(uint2*)(grow + 9216 + ot * 2) = make_uint2(l0 | (l1 << 16), l2 | (l3 << 16));
          }
        }
      }
      __syncthreads();                          // gel planes visible
      #pragma unroll
      for (int kc = 0; kc < 2; ++kc) {
        bf16x8 ao[2][3];
        #pragma unroll
        for (int ot = 0; ot < 2; ++ot)
          #pragma unroll
          for (int p = 0; p < 3; ++p)
            ao[ot][p] = *(const bf16x8*)(wospl + p * 32768 +
                ((or2 * 32 + ot * 16 + ln) * 256 + qblk * 128 + ph * 64 + kc * 32 + kb * 8));
        #pragma unroll
        for (int yt = 0; yt < 4; ++yt) {
          const float* bp = gel + ((yc * 4 + yt) * 16 + ln) * 36 + kc * 16 + kb * 4;
          bf16x8 B0 = *(const bf16x8*)(bp);
          bf16x8 B1 = *(const bf16x8*)(bp + 4608);
          bf16x8 B2 = *(const bf16x8*)(bp + 9216);
          #pragma unroll
          for (int ot = 0; ot < 2; ++ot)
            oacc[ot][yt] = mfma6(ao[ot][0], ao[ot][1], ao[ot][2], B0, B1, B2, oacc[ot][yt]);
        }
      }
    }
  }

  // ---- LN1 over y per o-row (acc layout: o = or2*32+ot*16+kb*4+r, y = (yc*4+yt)*16+ln) ----
  __syncthreads();
  float* red_s = sm;
  float* red_q = sm + 4096;
  #pragma unroll
  for (int ot = 0; ot < 2; ++ot)
    #pragma unroll
    for (int r = 0; r < 4; ++r) {
      int o = or2 * 32 + ot * 16 + kb * 4 + r;
      float s = 0.0f, q = 0.0f;
      #pragma unroll
      for (int yt = 0; yt < 4; ++yt) { float v = oacc[ot][yt][r]; s += v; q = fmaf(v, v, q); }
      red_s[o * 32 + yc * 16 + ln] = s;
      red_q[o * 32 + yc * 16 + ln] = q;
    }
  __syncthreads();
  if (t < 128) {
    double s = 0.0, q = 0.0;
    #pragma unroll
    for (int i = 0; i < 32; ++i) { s += red_s[t * 32 + i]; q += red_q[t * 32 + i]; }
    double mu = s * (1.0 / 128.0);
    double var = q * (1.0 / 128.0) - mu * mu;
    lnm[t] = (float)mu;
    lnr[t] = (float)(1.0 / sqrt(var + 1e-5));
  }
  __syncthreads();
  float g1v[4], b1v[4];
  #pragma unroll
  for (int yt = 0; yt < 4; ++yt) {
    int y = (yc * 4 + yt) * 16 + ln;
    g1v[yt] = g1[y]; b1v[yt] = b1[y];
  }
  #pragma unroll
  for (int ot = 0; ot < 2; ++ot)
    #pragma unroll
    for (int r = 0; r < 4; ++r) {
      int o = or2 * 32 + ot * 16 + kb * 4 + r;
      float mu = lnm[o], rs = lnr[o];
      #pragma unroll
      for (int yt = 0; yt < 4; ++yt) {
        int y = (yc * 4 + yt) * 16 + ln;
        out[(((size_t)(b * 128 + o)) * 128 + x) * 128 + y] =
            (oacc[ot][yt][r] - mu) * rs * g1v[yt] + b1v[yt];
      }
    }
}

extern "C" void kernel_launch(void* const* d_in, const int* in_sizes, int n_in,
                              void* d_out, int out_size, void* d_ws, size_t ws_size,
                              hipStream_t stream) {
  const float* fmap = (const float*)d_in[0];
  const float* g0   = (const float*)d_in[1];
  const float* b0   = (const float*)d_in[2];
  const float* wqkv = (const float*)d_in[3];
  const float* wout = (const float*)d_in[4];
  const float* g1   = (const float*)d_in[5];
  const float* b1   = (const float*)d_in[6];
  float* ws  = (float*)d_ws;
  float* out = (float*)d_out;

  hipMemsetAsync((char*)d_ws + (size_t)OFF_CTXA * 4, 0, (size_t)2162688 * 4, stream);
  prep_kernel<<<512, 256, 0, stream>>>(wqkv, wout, ws);
  ln0_stats_kernel<<<65536, 256, 0, stream>>>(fmap, ws);
  kv_ctx_kernel<<<dim3(128, 16), 512, 0, stream>>>(fmap, g0, b0, ws);
  ctx_reduce_kernel<<<128, 256, 0, stream>>>(ws);
  final_kernel<<<dim3(128, 16), 512, 0, stream>>>(fmap, g0, b0, g1, b1, ws, out);
}

// Round 4
// 1042.969 us; speedup vs baseline: 1.2936x; 1.0005x over previous
//
#include <hip/hip_runtime.h>
#include <math.h>

// B=16, C=128, X=128, Y=128, heads=8, dh=32, inner=256
// ws layout (float offsets):
#define OFF_MU    0u          // [262144] per (b,c,x)
#define OFF_RSTD  262144u
#define OFF_CTXA  524288u     // [bh=128][xg=16][1056] atomic partials (U 1024 + sexp 32)
#define OFF_CTXP  2686976u    // sigma-permuted ctx: [bh=128][3 planes][32 e][32 k] bf16 (3072 shorts/bh)
#define OFF_WSPL  2883584u    // 3 bf16 planes of permuted k/v weights (65536 shorts/plane)
#define OFF_WQSPL 2981888u    // 3 bf16 planes of q weights [256 o][128 c] (32768 shorts/plane)
#define OFF_WOSPL 3031040u    // 3 bf16 planes of wout [128 o][256 k-sigma] (32768 shorts/plane)
                              // end: 3080192 floats = 12.32 MB

typedef __attribute__((ext_vector_type(8))) short bf16x8;
typedef __attribute__((ext_vector_type(4))) float f32x4;

__device__ __forceinline__ void split3(float v, unsigned& h, unsigned& m, unsigned& l) {
  unsigned u = __float_as_uint(v);
  float r1 = v - __uint_as_float(u & 0xffff0000u);
  unsigned u1 = __float_as_uint(r1);
  float r2 = r1 - __uint_as_float(u1 & 0xffff0000u);
  h = u >> 16; m = u1 >> 16; l = __float_as_uint(r2) >> 16;
}

// 6-product split-bf16 MFMA: A,B are 3-plane splits (h,m,l)
__device__ __forceinline__ f32x4 mfma6(const bf16x8& A0, const bf16x8& A1, const bf16x8& A2,
                                       const bf16x8& B0, const bf16x8& B1, const bf16x8& B2,
                                       f32x4 c) {
  c = __builtin_amdgcn_mfma_f32_16x16x32_bf16(A0, B0, c, 0, 0, 0);
  c = __builtin_amdgcn_mfma_f32_16x16x32_bf16(A0, B1, c, 0, 0, 0);
  c = __builtin_amdgcn_mfma_f32_16x16x32_bf16(A1, B0, c, 0, 0, 0);
  c = __builtin_amdgcn_mfma_f32_16x16x32_bf16(A0, B2, c, 0, 0, 0);
  c = __builtin_amdgcn_mfma_f32_16x16x32_bf16(A1, B1, c, 0, 0, 0);
  c = __builtin_amdgcn_mfma_f32_16x16x32_bf16(A2, B0, c, 0, 0, 0);
  return c;
}

// ---------------- prep: bf16 3-way weight splits ----------------
__global__ void prep_kernel(const float* __restrict__ wqkv,
                            const float* __restrict__ wout,
                            float* __restrict__ ws) {
  int idx = blockIdx.x * 256 + threadIdx.x;   // 512 blocks -> 131072
  float v;
  unsigned short* wp;
  unsigned plane, slot;
  if (idx < 65536) {
    // k/v weight rows, permuted per-blk
    int row = idx >> 7, c = idx & 127;   // row 0..511
    int blk = row >> 7, ol = row & 127;
    int hh = (ol >> 5) & 1;
    int src = ((ol & 64) ? 512 : 256) + (2 * blk + hh) * 32 + (ol & 31);
    v = wqkv[src * 128 + c];
    wp = (unsigned short*)(ws + OFF_WSPL);
    plane = 65536; slot = (unsigned)idx;
  } else if (idx < 98304) {
    // q weights: rows o=0..255 of wqkv, layout [o][c]
    int j = idx - 65536;
    v = wqkv[j];
    wp = (unsigned short*)(ws + OFF_WQSPL);
    plane = 32768; slot = (unsigned)j;
  } else {
    // wout sigma-permuted: dst slot [o][k], src cp within each 32-chunk:
    // k = kb*8+ot*4+r  <->  cp = ot*16+kb*4+r
    int j = idx - 98304;
    int o = j >> 8, k = j & 255;
    int cp = (k & 0xE0) | (((k >> 2) & 1) << 4) | (((k >> 3) & 3) << 2) | (k & 3);
    v = wout[o * 256 + cp];
    wp = (unsigned short*)(ws + OFF_WOSPL);
    plane = 32768; slot = (unsigned)j;
  }
  unsigned h, m, l;
  split3(v, h, m, l);
  wp[slot]             = (unsigned short)h;
  wp[plane + slot]     = (unsigned short)m;
  wp[2 * plane + slot] = (unsigned short)l;
}

// ---------------- K1: LN0 stats (fused) + all-heads K/V + context partials ----------------
__launch_bounds__(512, 4)
__global__ void kv_ctx_kernel(const float* __restrict__ fmap,
                              const float* __restrict__ g0,
                              const float* __restrict__ b0,
                              float* __restrict__ ws) {
  __shared__ float sm[13888];
  const int x = blockIdx.x, b = blockIdx.y, t = threadIdx.x;
  const int wave = t >> 6, lane = t & 63;
  const int ln = lane & 15, kb = lane >> 4;
  const int or2 = wave >> 1, yc = wave & 1;
  const int dt = lane >> 3, et = lane & 7;
  const int xg = x >> 3;

  float* pb  = sm;            // [64][36]
  float* vb  = sm + 2304;     // [64][36]
  float* vss = sm + 4608;     // [4][64]
  float* ser = sm + 4864;     // [8][8][4]
  float* rnS = sm + 5120;     // [64]
  float* red = sm + 5184;     // [512][16] (aliases planes)
  float* pls = sm + 5184;     // 3 planes x [128 y][20 dw]
  float* muS = sm + 13376;
  float* rsS = sm + 13504;
  float* g0S = sm + 13632;
  float* b0S = sm + 13760;
  float* fmS = sm;            // [32][128] (aliases pb/vb)

  // ---- LN0 stats for this (b,x): 128 rows over y, computed in-block ----
  {
    const int r = t >> 2, q = t & 3;          // row c = r, y-quarter q
    const float* p = fmap + (((size_t)(b * 128 + r)) * 128 + x) * 128 + q * 32;
    double s = 0.0, qq = 0.0;
    #pragma unroll
    for (int i = 0; i < 8; ++i) {
      float4 v4 = *(const float4*)(p + i * 4);
      s  += (double)v4.x + (double)v4.y + (double)v4.z + (double)v4.w;
      qq += (double)v4.x * v4.x + (double)v4.y * v4.y
          + (double)v4.z * v4.z + (double)v4.w * v4.w;
    }
    s += __shfl_xor(s, 1); qq += __shfl_xor(qq, 1);
    s += __shfl_xor(s, 2); qq += __shfl_xor(qq, 2);
    if (q == 0) {
      double mu = s * (1.0 / 128.0);
      double var = qq * (1.0 / 128.0) - mu * mu;
      float muf = (float)mu, rsf = (float)(1.0 / sqrt(var + 1e-5));
      muS[r] = muf; rsS[r] = rsf;
      ws[OFF_MU + (unsigned)((b * 128 + r) * 128 + x)] = muf;
      ws[OFF_RSTD + (unsigned)((b * 128 + r) * 128 + x)] = rsf;
    }
  }
  if (t < 128) { g0S[t] = g0[t]; b0S[t] = b0[t]; }

  const unsigned short* wspl = (const unsigned short*)(ws + OFF_WSPL);

  for (int blk = 0; blk < 4; ++blk) {
    f32x4 acc[2][4];
    #pragma unroll
    for (int i = 0; i < 2; ++i)
      #pragma unroll
      for (int j = 0; j < 4; ++j) acc[i][j] = (f32x4){0.f, 0.f, 0.f, 0.f};

    for (int cc = 0; cc < 4; ++cc) {
      bf16x8 af[2][3];
      #pragma unroll
      for (int ot = 0; ot < 2; ++ot)
        #pragma unroll
        for (int p = 0; p < 3; ++p)
          af[ot][p] = *(const bf16x8*)(wspl + p * 65536 +
              ((blk * 128 + or2 * 32 + ot * 16 + ln) * 128 + cc * 32 + kb * 8));

      __syncthreads();
      #pragma unroll
      for (int it = 0; it < 2; ++it) {
        int idx4 = it * 512 + t;
        int c = idx4 >> 5, y4 = (idx4 & 31) * 4;
        int cg = cc * 32 + c;
        const float4 r = *(const float4*)(fmap + (((size_t)(b * 128 + cg)) * 128 + x) * 128 + y4);
        float mu = muS[cg], rs = rsS[cg];
        float4 g = *(const float4*)(g0S + y4);
        float4 be = *(const float4*)(b0S + y4);
        float4 o;
        o.x = (r.x - mu) * rs * g.x + be.x;
        o.y = (r.y - mu) * rs * g.y + be.y;
        o.z = (r.z - mu) * rs * g.z + be.z;
        o.w = (r.w - mu) * rs * g.w + be.w;
        *(float4*)(fmS + c * 128 + y4) = o;
      }
      __syncthreads();
      {                                         // transpose + 3-way bf16 split
        const int ty = t & 127, cg = t >> 7;
        unsigned int d0[4], d1[4], d2[4];
        #pragma unroll
        for (int jj = 0; jj < 4; ++jj) {
          unsigned int h[2], m[2], l[2];
          #pragma unroll
          for (int e = 0; e < 2; ++e) {
            float v = fmS[(cg * 8 + jj * 2 + e) * 128 + ty];
            split3(v, h[e], m[e], l[e]);
          }
          d0[jj] = h[0] | (h[1] << 16);
          d1[jj] = m[0] | (m[1] << 16);
          d2[jj] = l[0] | (l[1] << 16);
        }
        float* pp = pls + ty * 20 + cg * 4;
        *reinterpret_cast<uint4*>(pp)        = make_uint4(d0[0], d0[1], d0[2], d0[3]);
        *reinterpret_cast<uint4*>(pp + 2560) = make_uint4(d1[0], d1[1], d1[2], d1[3]);
        *reinterpret_cast<uint4*>(pp + 5120) = make_uint4(d2[0], d2[1], d2[2], d2[3]);
      }
      __syncthreads();
      #pragma unroll
      for (int yt = 0; yt < 4; ++yt) {
        const float* bp = pls + ((yc * 4 + yt) * 16 + ln) * 20 + kb * 4;
        bf16x8 B0 = *(const bf16x8*)(bp);
        bf16x8 B1 = *(const bf16x8*)(bp + 2560);
        bf16x8 B2 = *(const bf16x8*)(bp + 5120);
        #pragma unroll
        for (int ot = 0; ot < 2; ++ot)
          acc[ot][yt] = mfma6(af[ot][0], af[ot][1], af[ot][2], B0, B1, B2, acc[ot][yt]);
      }
    }

    for (int hh = 0; hh < 2; ++hh) {
      float u[16], se[4];
      #pragma unroll
      for (int i = 0; i < 16; ++i) u[i] = 0.0f;
      se[0] = se[1] = se[2] = se[3] = 0.0f;

      for (int hf = 0; hf < 2; ++hf) {
        if (wave == hh * 2 + hf) {
          #pragma unroll
          for (int ot = 0; ot < 2; ++ot)
            #pragma unroll
            for (int yt = 0; yt < 4; ++yt) {
              f32x4 a = acc[ot][yt];
              float4 p;
              p.x = __expf(a[0]); p.y = __expf(a[1]);
              p.z = __expf(a[2]); p.w = __expf(a[3]);
              *(float4*)(pb + (yt * 16 + ln) * 36 + ot * 16 + kb * 4) = p;
            }
        }
        if (wave == 4 + hh * 2 + hf) {
          #pragma unroll
          for (int yt = 0; yt < 4; ++yt) {
            f32x4 a0 = acc[0][yt], a1 = acc[1][yt];
            int yl = yt * 16 + ln;
            *(float4*)(vb + yl * 36 + kb * 4)      = make_float4(a0[0], a0[1], a0[2], a0[3]);
            *(float4*)(vb + yl * 36 + 16 + kb * 4) = make_float4(a1[0], a1[1], a1[2], a1[3]);
            float s = a0[0] * a0[0] + a0[1] * a0[1] + a0[2] * a0[2] + a0[3] * a0[3]
                    + a1[0] * a1[0] + a1[1] * a1[1] + a1[2] * a1[2] + a1[3] * a1[3];
            vss[kb * 64 + yl] = s;
          }
        }
        __syncthreads();
        if (t < 64) {
          float s2 = vss[t] + vss[64 + t] + vss[128 + t] + vss[192 + t];
          rnS[t] = 1.0f / fmaxf(sqrtf(s2), 1e-12f);
        }
        __syncthreads();
        #pragma unroll 2
        for (int yy = 0; yy < 8; ++yy) {
          int y = wave * 8 + yy;
          const float4 p = *(const float4*)(pb + y * 36 + dt * 4);
          float4 v = *(const float4*)(vb + y * 36 + et * 4);
          float rn = rnS[y];
          v.x *= rn; v.y *= rn; v.z *= rn; v.w *= rn;
          se[0] += p.x; se[1] += p.y; se[2] += p.z; se[3] += p.w;
          u[0]  = fmaf(p.x, v.x, u[0]);  u[1]  = fmaf(p.x, v.y, u[1]);
          u[2]  = fmaf(p.x, v.z, u[2]);  u[3]  = fmaf(p.x, v.w, u[3]);
          u[4]  = fmaf(p.y, v.x, u[4]);  u[5]  = fmaf(p.y, v.y, u[5]);
          u[6]  = fmaf(p.y, v.z, u[6]);  u[7]  = fmaf(p.y, v.w, u[7]);
          u[8]  = fmaf(p.z, v.x, u[8]);  u[9]  = fmaf(p.z, v.y, u[9]);
          u[10] = fmaf(p.z, v.z, u[10]); u[11] = fmaf(p.z, v.w, u[11]);
          u[12] = fmaf(p.w, v.x, u[12]); u[13] = fmaf(p.w, v.y, u[13]);
          u[14] = fmaf(p.w, v.z, u[14]); u[15] = fmaf(p.w, v.w, u[15]);
        }
        __syncthreads();
      }
      *(float4*)(red + t * 16 + 0)  = make_float4(u[0], u[1], u[2], u[3]);
      *(float4*)(red + t * 16 + 4)  = make_float4(u[4], u[5], u[6], u[7]);
      *(float4*)(red + t * 16 + 8)  = make_float4(u[8], u[9], u[10], u[11]);
      *(float4*)(red + t * 16 + 12) = make_float4(u[12], u[13], u[14], u[15]);
      if (et == 0)
        *(float4*)(ser + (wave * 8 + dt) * 4) = make_float4(se[0], se[1], se[2], se[3]);
      __syncthreads();
      {
        const int tile = t >> 3;
        const int i0 = (t & 7) * 2;
        float s0 = 0.0f, s1 = 0.0f;
        #pragma unroll
        for (int w = 0; w < 8; ++w) {
          s0 += red[(w * 64 + tile) * 16 + i0];
          s1 += red[(w * 64 + tile) * 16 + i0 + 1];
        }
        const int d = (tile >> 3) * 4 + (i0 >> 2);
        const int e = (tile & 7) * 4 + (i0 & 3);
        float* ca = ws + OFF_CTXA + ((size_t)(b * 8 + blk * 2 + hh) * 16 + xg) * 1056;
        atomicAdd(ca + d * 32 + e, s0);
        atomicAdd(ca + d * 32 + e + 1, s1);
        if (t < 32) {
          float ss = 0.0f;
          #pragma unroll
          for (int w = 0; w < 8; ++w) ss += ser[(w * 8 + (t >> 2)) * 4 + (t & 3)];
          atomicAdd(ca + 1024 + t, ss);
        }
      }
    }
  }
}

// ---------------- reduce x-group partials, fold scales, emit sigma-permuted bf16 planes ----------------
__global__ void ctx_reduce_kernel(float* __restrict__ ws) {
  __shared__ float sume[32];
  const int bh = blockIdx.x, t = threadIdx.x;
  const float* ca = ws + OFF_CTXA + (size_t)bh * 16 * 1056;
  if (t < 32) {
    double a = 0.0;
    #pragma unroll
    for (int xg = 0; xg < 16; ++xg) a += ca[xg * 1056 + 1024 + t];
    sume[t] = (float)a;
  }
  __syncthreads();
  const double sb = (1.0 / 16384.0) * 0.17677669529663688;  // inv^2 * dh^-0.5
  unsigned short* cp = (unsigned short*)(ws + OFF_CTXP) + (size_t)bh * 3072;
  #pragma unroll
  for (int i = 0; i < 4; ++i) {
    int de = t + 256 * i;
    int d = de >> 5, e = de & 31;
    double a = 0.0;
    #pragma unroll
    for (int xg = 0; xg < 16; ++xg) a += ca[xg * 1056 + de];
    float v = (float)(a * sb / (double)sume[d]);
    // sigma: k = kb*8 + ot*4 + r with d = ot*16 + kb*4 + r
    int k = ((d >> 2) & 3) * 8 + ((d >> 4) & 1) * 4 + (d & 3);
    unsigned h, m, l;
    split3(v, h, m, l);
    cp[e * 32 + k]        = (unsigned short)h;
    cp[1024 + e * 32 + k] = (unsigned short)m;
    cp[2048 + e * 32 + k] = (unsigned short)l;
  }
}

// ---------------- final v4: Q-MFMA -> per-yt {softmax, ctx-MFMA, gelu} -> out-conv MFMA -> LN1 ----------------
// Per-yt restructure keeps peak VGPR liveness ~110 (< the 128 cap from launch_bounds) -> no scratch.
// LDS floats: staging fmS[32][128]@0 + pls 3x[128][20]@4096 (11776); gel planes 3x[128][36]@0
// (13824, alias staging); muS@13824,rsS,g0S,b0S, lnm@14336, lnr@14464 -> 14592 floats = 58.4 KB
__launch_bounds__(512, 4)
__global__ void final_kernel(const float* __restrict__ fmap,
                             const float* __restrict__ g0,
                             const float* __restrict__ b0,
                             const float* __restrict__ g1,
                             const float* __restrict__ b1,
                             const float* __restrict__ ws,
                             float* __restrict__ out) {
  __shared__ float sm[14592];
  const int x = blockIdx.x, b = blockIdx.y, t = threadIdx.x;
  const int wave = t >> 6, lane = t & 63;
  const int ln = lane & 15, kb = lane >> 4;   // MFMA fragment coords
  const int or2 = wave >> 1, yc = wave & 1;   // wave tile: o-tiles(or head) x y-halves

  float* fmS = sm;            // [32][128] staging
  float* pls = sm + 4096;     // 3 planes x [128][20] staging splits
  float* gel = sm;            // 3 planes x [128][36] gel splits (aliases staging)
  float* muS = sm + 13824;
  float* rsS = sm + 13952;
  float* g0S = sm + 14080;
  float* b0S = sm + 14208;
  float* lnm = sm + 14336;
  float* lnr = sm + 14464;

  if (t < 128) {
    muS[t] = ws[OFF_MU + (unsigned)((b * 128 + t) * 128 + x)];
    rsS[t] = ws[OFF_RSTD + (unsigned)((b * 128 + t) * 128 + x)];
  } else if (t < 256) g0S[t - 128] = g0[t - 128];
  else if (t < 384) b0S[t - 256] = b0[t - 256];

  const unsigned short* wqspl = (const unsigned short*)(ws + OFF_WQSPL);
  const unsigned short* wospl = (const unsigned short*)(ws + OFF_WOSPL);
  const unsigned short* ctxp  = (const unsigned short*)(ws + OFF_CTXP);

  f32x4 oacc[2][4];
  #pragma unroll
  for (int i = 0; i < 2; ++i)
    #pragma unroll
    for (int j = 0; j < 4; ++j) oacc[i][j] = (f32x4){0.f, 0.f, 0.f, 0.f};

  for (int qblk = 0; qblk < 2; ++qblk) {
    f32x4 qacc[2][4];
    #pragma unroll
    for (int i = 0; i < 2; ++i)
      #pragma unroll
      for (int j = 0; j < 4; ++j) qacc[i][j] = (f32x4){0.f, 0.f, 0.f, 0.f};

    // ---- Q matmul over 4 c-chunks ----
    for (int cc = 0; cc < 4; ++cc) {
      bf16x8 af[2][3];
      #pragma unroll
      for (int ot = 0; ot < 2; ++ot)
        #pragma unroll
        for (int p = 0; p < 3; ++p)
          af[ot][p] = *(const bf16x8*)(wqspl + p * 32768 +
              ((qblk * 128 + or2 * 32 + ot * 16 + ln) * 128 + cc * 32 + kb * 8));

      __syncthreads();                          // staging region free of prior readers
      #pragma unroll
      for (int it = 0; it < 2; ++it) {          // stage fm chunk, LN0 applied (f32)
        int idx4 = it * 512 + t;
        int c = idx4 >> 5, y4 = (idx4 & 31) * 4;
        int cg = cc * 32 + c;
        const float4 r = *(const float4*)(fmap + (((size_t)(b * 128 + cg)) * 128 + x) * 128 + y4);
        float mu = muS[cg], rs = rsS[cg];
        float4 g = *(const float4*)(g0S + y4);
        float4 be = *(const float4*)(b0S + y4);
        float4 o;
        o.x = (r.x - mu) * rs * g.x + be.x;
        o.y = (r.y - mu) * rs * g.y + be.y;
        o.z = (r.z - mu) * rs * g.z + be.z;
        o.w = (r.w - mu) * rs * g.w + be.w;
        *(float4*)(fmS + c * 128 + y4) = o;
      }
      __syncthreads();
      {                                         // transpose + 3-way bf16 split
        const int ty = t & 127, cg = t >> 7;
        unsigned int d0[4], d1[4], d2[4];
        #pragma unroll
        for (int jj = 0; jj < 4; ++jj) {
          unsigned int h[2], m[2], l[2];
          #pragma unroll
          for (int e = 0; e < 2; ++e) {
            float v = fmS[(cg * 8 + jj * 2 + e) * 128 + ty];
            split3(v, h[e], m[e], l[e]);
          }
          d0[jj] = h[0] | (h[1] << 16);
          d1[jj] = m[0] | (m[1] << 16);
          d2[jj] = l[0] | (l[1] << 16);
        }
        float* pp = pls + ty * 20 + cg * 4;
        *reinterpret_cast<uint4*>(pp)        = make_uint4(d0[0], d0[1], d0[2], d0[3]);
        *reinterpret_cast<uint4*>(pp + 2560) = make_uint4(d1[0], d1[1], d1[2], d1[3]);
        *reinterpret_cast<uint4*>(pp + 5120) = make_uint4(d2[0], d2[1], d2[2], d2[3]);
      }
      __syncthreads();
      #pragma unroll
      for (int yt = 0; yt < 4; ++yt) {
        const float* bp = pls + ((yc * 4 + yt) * 16 + ln) * 20 + kb * 4;
        bf16x8 B0 = *(const bf16x8*)(bp);
        bf16x8 B1 = *(const bf16x8*)(bp + 2560);
        bf16x8 B2 = *(const bf16x8*)(bp + 5120);
        #pragma unroll
        for (int ot = 0; ot < 2; ++ot)
          qacc[ot][yt] = mfma6(af[ot][0], af[ot][1], af[ot][2], B0, B1, B2, qacc[ot][yt]);
      }
    }

    // ---- per-yt: exp + ssum + pack + ctx-MFMA + gelu (minimal liveness; qacc dies per yt) ----
    // lane holds d = ot*16+kb*4+r at y = (yc*4+yt)*16+ln; B-frag k = kb*8+ot*4+r == own values
    f32x4 ge[2][4];
    const unsigned short* chp = ctxp + (size_t)(b * 8 + qblk * 4 + or2) * 3072;
    #pragma unroll
    for (int yt = 0; yt < 4; ++yt) {
      float pv[8];
      #pragma unroll
      for (int ot = 0; ot < 2; ++ot)
        #pragma unroll
        for (int r = 0; r < 4; ++r)
          pv[ot * 4 + r] = __expf(qacc[ot][yt][r]);
      float ps = ((pv[0] + pv[1]) + (pv[2] + pv[3])) + ((pv[4] + pv[5]) + (pv[6] + pv[7]));
      ps += __shfl_xor(ps, 16);
      ps += __shfl_xor(ps, 32);
      const float rs = 1.0f / ps;
      unsigned wh[4], wm[4], wl[4];
      #pragma unroll
      for (int j = 0; j < 4; ++j) {
        unsigned h0, m0, l0, h1, m1, l1;
        split3(pv[2 * j], h0, m0, l0);
        split3(pv[2 * j + 1], h1, m1, l1);
        wh[j] = h0 | (h1 << 16);
        wm[j] = m0 | (m1 << 16);
        wl[j] = l0 | (l1 << 16);
      }
      uint4 uh = make_uint4(wh[0], wh[1], wh[2], wh[3]);
      uint4 um = make_uint4(wm[0], wm[1], wm[2], wm[3]);
      uint4 ul = make_uint4(wl[0], wl[1], wl[2], wl[3]);
      bf16x8 P0 = *(const bf16x8*)&uh;
      bf16x8 P1 = *(const bf16x8*)&um;
      bf16x8 P2 = *(const bf16x8*)&ul;
      // opaque per-yt offset: break CSE/LICM so ctx A-frags are NOT hoisted
      // out of the yt loop into 48 long-lived VGPRs (the round-3 spill source)
      unsigned off = (unsigned)((0 * 16 + ln) * 32 + kb * 8);
      asm volatile("" : "+v"(off));
      #pragma unroll
      for (int ot = 0; ot < 2; ++ot) {
        bf16x8 aq0 = *(const bf16x8*)(chp +        off + ot * 512);
        bf16x8 aq1 = *(const bf16x8*)(chp + 1024 + off + ot * 512);
        bf16x8 aq2 = *(const bf16x8*)(chp + 2048 + off + ot * 512);
        f32x4 g = mfma6(aq0, aq1, aq2, P0, P1, P2, (f32x4){0.f, 0.f, 0.f, 0.f});
        #pragma unroll
        for (int r = 0; r < 4; ++r) {
          float v = g[r] * rs;
          ge[ot][yt][r] = 0.5f * v * (1.0f + erff(v * 0.70710678118654752f));
        }
      }
    }

    // ---- out-conv in 2 phases of K=64 (heads {2ph, 2ph+1}) ----
    for (int ph = 0; ph < 2; ++ph) {
      __syncthreads();                          // prior readers of gel region done
      if ((or2 >> 1) == ph) {                   // this wave's head is in the chunk
        const int c16 = (or2 & 1) * 16;
        #pragma unroll
        for (int yt = 0; yt < 4; ++yt) {
          float* grow = gel + ((yc * 4 + yt) * 16 + ln) * 36 + c16 + kb * 4;
          #pragma unroll
          for (int ot = 0; ot < 2; ++ot) {
            unsigned h0, m0, l0, h1, m1, l1, h2, m2, l2, h3, m3, l3;
            split3(ge[ot][yt][0], h0, m0, l0);
            split3(ge[ot][yt][1], h1, m1, l1);
            split3(ge[ot][yt][2], h2, m2, l2);
            split3(ge[ot][yt][3], h3, m3, l3);
            *(uint2*)(grow + ot * 2)        = make_uint2(h0 | (h1 << 16), h2 | (h3 << 16));
            *(uint2*)(grow + 4608 + ot * 2) = make_uint2(m0 | (m1 << 16), m2 | (m3 << 16));
            *(uint2*)(grow + 9216 + ot * 2) = make_uint2(l0 | (l1 << 16), l2 | (l3 << 16));
          }
        }
      }
      __syncthreads();                          // gel planes visible
      #pragma unroll
      for (int kc = 0; kc < 2; ++kc) {
        bf16x8 ao[2][3];
        #pragma unroll
        for (int ot = 0; ot < 2; ++ot)
          #pragma unroll
          for (int p = 0; p < 3; ++p)
            ao[ot][p] = *(const bf16x8*)(wospl + p * 32768 +
                ((or2 * 32 + ot * 16 + ln) * 256 + qblk * 128 + ph * 64 + kc * 32 + kb * 8));
        #pragma unroll
        for (int yt = 0; yt < 4; ++yt) {
          const float* bp = gel + ((yc * 4 + yt) * 16 + ln) * 36 + kc * 16 + kb * 4;
          bf16x8 B0 = *(const bf16x8*)(bp);
          bf16x8 B1 = *(const bf16x8*)(bp + 4608);
          bf16x8 B2 = *(const bf16x8*)(bp + 9216);
          #pragma unroll
          for (int ot = 0; ot < 2; ++ot)
            oacc[ot][yt] = mfma6(ao[ot][0], ao[ot][1], ao[ot][2], B0, B1, B2, oacc[ot][yt]);
        }
      }
    }
  }

  // ---- LN1 over y per o-row (acc layout: o = or2*32+ot*16+kb*4+r, y = (yc*4+yt)*16+ln) ----
  __syncthreads();
  float* red_s = sm;
  float* red_q = sm + 4096;
  #pragma unroll
  for (int ot = 0; ot < 2; ++ot)
    #pragma unroll
    for (int r = 0; r < 4; ++r) {
      int o = or2 * 32 + ot * 16 + kb * 4 + r;
      float s = 0.0f, q = 0.0f;
      #pragma unroll
      for (int yt = 0; yt < 4; ++yt) { float v = oacc[ot][yt][r]; s += v; q = fmaf(v, v, q); }
      red_s[o * 32 + yc * 16 + ln] = s;
      red_q[o * 32 + yc * 16 + ln] = q;
    }
  __syncthreads();
  if (t < 128) {
    double s = 0.0, q = 0.0;
    #pragma unroll
    for (int i = 0; i < 32; ++i) { s += red_s[t * 32 + i]; q += red_q[t * 32 + i]; }
    double mu = s * (1.0 / 128.0);
    double var = q * (1.0 / 128.0) - mu * mu;
    lnm[t] = (float)mu;
    lnr[t] = (float)(1.0 / sqrt(var + 1e-5));
  }
  __syncthreads();
  float g1v[4], b1v[4];
  #pragma unroll
  for (int yt = 0; yt < 4; ++yt) {
    int y = (yc * 4 + yt) * 16 + ln;
    g1v[yt] = g1[y]; b1v[yt] = b1[y];
  }
  #pragma unroll
  for (int ot = 0; ot < 2; ++ot)
    #pragma unroll
    for (int r = 0; r < 4; ++r) {
      int o = or2 * 32 + ot * 16 + kb * 4 + r;
      float mu = lnm[o], rs = lnr[o];
      #pragma unroll
      for (int yt = 0; yt < 4; ++yt) {
        int y = (yc * 4 + yt) * 16 + ln;
        out[(((size_t)(b * 128 + o)) * 128 + x) * 128 + y] =
            (oacc[ot][yt][r] - mu) * rs * g1v[yt] + b1v[yt];
      }
    }
}

extern "C" void kernel_launch(void* const* d_in, const int* in_sizes, int n_in,
                              void* d_out, int out_size, void* d_ws, size_t ws_size,
                              hipStream_t stream) {
  const float* fmap = (const float*)d_in[0];
  const float* g0   = (const float*)d_in[1];
  const float* b0   = (const float*)d_in[2];
  const float* wqkv = (const float*)d_in[3];
  const float* wout = (const float*)d_in[4];
  const float* g1   = (const float*)d_in[5];
  const float* b1   = (const float*)d_in[6];
  float* ws  = (float*)d_ws;
  float* out = (float*)d_out;

  hipMemsetAsync((char*)d_ws + (size_t)OFF_CTXA * 4, 0, (size_t)2162688 * 4, stream);
  prep_kernel<<<512, 256, 0, stream>>>(wqkv, wout, ws);
  kv_ctx_kernel<<<dim3(128, 16), 512, 0, stream>>>(fmap, g0, b0, ws);
  ctx_reduce_kernel<<<128, 256, 0, stream>>>(ws);
  final_kernel<<<dim3(128, 16), 512, 0, stream>>>(fmap, g0, b0, g1, b1, ws, out);
}

// Round 5
// 883.877 us; speedup vs baseline: 1.5264x; 1.1800x over previous
//
#include <hip/hip_runtime.h>
#include <math.h>

// B=16, C=128, X=128, Y=128, heads=8, dh=32, inner=256
// ws layout (float offsets):
#define OFF_MU    0u          // [262144] per (b,c,x)
#define OFF_RSTD  262144u
#define OFF_CTXA  524288u     // [bh=128][xg=16][1056] atomic partials (U 1024 + sexp 32)
#define OFF_CTXP  2686976u    // sigma-permuted ctx: [bh=128][3 planes][32 e][32 k] bf16 (3072 shorts/bh)
#define OFF_WSPL  2883584u    // 3 bf16 planes of permuted k/v weights (65536 shorts/plane)
#define OFF_WQSPL 2981888u    // 3 bf16 planes of q weights [256 o][128 c] (32768 shorts/plane)
#define OFF_WOSPL 3031040u    // 3 bf16 planes of wout [128 o][256 k-sigma] (32768 shorts/plane)
                              // end: 3080192 floats = 12.32 MB

typedef __attribute__((ext_vector_type(8))) short bf16x8;
typedef __attribute__((ext_vector_type(4))) float f32x4;

__device__ __forceinline__ void split3(float v, unsigned& h, unsigned& m, unsigned& l) {
  unsigned u = __float_as_uint(v);
  float r1 = v - __uint_as_float(u & 0xffff0000u);
  unsigned u1 = __float_as_uint(r1);
  float r2 = r1 - __uint_as_float(u1 & 0xffff0000u);
  h = u >> 16; m = u1 >> 16; l = __float_as_uint(r2) >> 16;
}

// 6-product split-bf16 MFMA: A,B are 3-plane splits (h,m,l)
__device__ __forceinline__ f32x4 mfma6(const bf16x8& A0, const bf16x8& A1, const bf16x8& A2,
                                       const bf16x8& B0, const bf16x8& B1, const bf16x8& B2,
                                       f32x4 c) {
  c = __builtin_amdgcn_mfma_f32_16x16x32_bf16(A0, B0, c, 0, 0, 0);
  c = __builtin_amdgcn_mfma_f32_16x16x32_bf16(A0, B1, c, 0, 0, 0);
  c = __builtin_amdgcn_mfma_f32_16x16x32_bf16(A1, B0, c, 0, 0, 0);
  c = __builtin_amdgcn_mfma_f32_16x16x32_bf16(A0, B2, c, 0, 0, 0);
  c = __builtin_amdgcn_mfma_f32_16x16x32_bf16(A1, B1, c, 0, 0, 0);
  c = __builtin_amdgcn_mfma_f32_16x16x32_bf16(A2, B0, c, 0, 0, 0);
  return c;
}

// ---------------- prep: bf16 3-way weight splits ----------------
__global__ void prep_kernel(const float* __restrict__ wqkv,
                            const float* __restrict__ wout,
                            float* __restrict__ ws) {
  int idx = blockIdx.x * 256 + threadIdx.x;   // 512 blocks -> 131072
  float v;
  unsigned short* wp;
  unsigned plane, slot;
  if (idx < 65536) {
    // k/v weight rows, permuted per-blk
    int row = idx >> 7, c = idx & 127;   // row 0..511
    int blk = row >> 7, ol = row & 127;
    int hh = (ol >> 5) & 1;
    int src = ((ol & 64) ? 512 : 256) + (2 * blk + hh) * 32 + (ol & 31);
    v = wqkv[src * 128 + c];
    wp = (unsigned short*)(ws + OFF_WSPL);
    plane = 65536; slot = (unsigned)idx;
  } else if (idx < 98304) {
    // q weights: rows o=0..255 of wqkv, layout [o][c]
    int j = idx - 65536;
    v = wqkv[j];
    wp = (unsigned short*)(ws + OFF_WQSPL);
    plane = 32768; slot = (unsigned)j;
  } else {
    // wout sigma-permuted: dst slot [o][k], src cp within each 32-chunk:
    // k = kb*8+ot*4+r  <->  cp = ot*16+kb*4+r
    int j = idx - 98304;
    int o = j >> 8, k = j & 255;
    int cp = (k & 0xE0) | (((k >> 2) & 1) << 4) | (((k >> 3) & 3) << 2) | (k & 3);
    v = wout[o * 256 + cp];
    wp = (unsigned short*)(ws + OFF_WOSPL);
    plane = 32768; slot = (unsigned)j;
  }
  unsigned h, m, l;
  split3(v, h, m, l);
  wp[slot]             = (unsigned short)h;
  wp[plane + slot]     = (unsigned short)m;
  wp[2 * plane + slot] = (unsigned short)l;
}

// ---------------- K1: LN0 stats (fused) + all-heads K/V + context partials ----------------
__launch_bounds__(512, 4)
__global__ void kv_ctx_kernel(const float* __restrict__ fmap,
                              const float* __restrict__ g0,
                              const float* __restrict__ b0,
                              float* __restrict__ ws) {
  __shared__ float sm[13888];
  const int x = blockIdx.x, b = blockIdx.y, t = threadIdx.x;
  const int wave = t >> 6, lane = t & 63;
  const int ln = lane & 15, kb = lane >> 4;
  const int or2 = wave >> 1, yc = wave & 1;
  const int dt = lane >> 3, et = lane & 7;
  const int xg = x >> 3;

  float* pb  = sm;            // [64][36]
  float* vb  = sm + 2304;     // [64][36]
  float* vss = sm + 4608;     // [4][64]
  float* ser = sm + 4864;     // [8][8][4]
  float* rnS = sm + 5120;     // [64]
  float* red = sm + 5184;     // [512][16] (aliases planes)
  float* pls = sm + 5184;     // 3 planes x [128 y][20 dw]
  float* muS = sm + 13376;
  float* rsS = sm + 13504;
  float* g0S = sm + 13632;
  float* b0S = sm + 13760;
  float* fmS = sm;            // [32][128] (aliases pb/vb)

  // ---- LN0 stats for this (b,x): 128 rows over y, computed in-block ----
  {
    const int r = t >> 2, q = t & 3;          // row c = r, y-quarter q
    const float* p = fmap + (((size_t)(b * 128 + r)) * 128 + x) * 128 + q * 32;
    double s = 0.0, qq = 0.0;
    #pragma unroll
    for (int i = 0; i < 8; ++i) {
      float4 v4 = *(const float4*)(p + i * 4);
      s  += (double)v4.x + (double)v4.y + (double)v4.z + (double)v4.w;
      qq += (double)v4.x * v4.x + (double)v4.y * v4.y
          + (double)v4.z * v4.z + (double)v4.w * v4.w;
    }
    s += __shfl_xor(s, 1); qq += __shfl_xor(qq, 1);
    s += __shfl_xor(s, 2); qq += __shfl_xor(qq, 2);
    if (q == 0) {
      double mu = s * (1.0 / 128.0);
      double var = qq * (1.0 / 128.0) - mu * mu;
      float muf = (float)mu, rsf = (float)(1.0 / sqrt(var + 1e-5));
      muS[r] = muf; rsS[r] = rsf;
      ws[OFF_MU + (unsigned)((b * 128 + r) * 128 + x)] = muf;
      ws[OFF_RSTD + (unsigned)((b * 128 + r) * 128 + x)] = rsf;
    }
  }
  if (t < 128) { g0S[t] = g0[t]; b0S[t] = b0[t]; }

  const unsigned short* wspl = (const unsigned short*)(ws + OFF_WSPL);

  for (int blk = 0; blk < 4; ++blk) {
    f32x4 acc[2][4];
    #pragma unroll
    for (int i = 0; i < 2; ++i)
      #pragma unroll
      for (int j = 0; j < 4; ++j) acc[i][j] = (f32x4){0.f, 0.f, 0.f, 0.f};

    for (int cc = 0; cc < 4; ++cc) {
      bf16x8 af[2][3];
      #pragma unroll
      for (int ot = 0; ot < 2; ++ot)
        #pragma unroll
        for (int p = 0; p < 3; ++p)
          af[ot][p] = *(const bf16x8*)(wspl + p * 65536 +
              ((blk * 128 + or2 * 32 + ot * 16 + ln) * 128 + cc * 32 + kb * 8));

      __syncthreads();
      #pragma unroll
      for (int it = 0; it < 2; ++it) {
        int idx4 = it * 512 + t;
        int c = idx4 >> 5, y4 = (idx4 & 31) * 4;
        int cg = cc * 32 + c;
        const float4 r = *(const float4*)(fmap + (((size_t)(b * 128 + cg)) * 128 + x) * 128 + y4);
        float mu = muS[cg], rs = rsS[cg];
        float4 g = *(const float4*)(g0S + y4);
        float4 be = *(const float4*)(b0S + y4);
        float4 o;
        o.x = (r.x - mu) * rs * g.x + be.x;
        o.y = (r.y - mu) * rs * g.y + be.y;
        o.z = (r.z - mu) * rs * g.z + be.z;
        o.w = (r.w - mu) * rs * g.w + be.w;
        *(float4*)(fmS + c * 128 + y4) = o;
      }
      __syncthreads();
      {                                         // transpose + 3-way bf16 split
        const int ty = t & 127, cg = t >> 7;
        unsigned int d0[4], d1[4], d2[4];
        #pragma unroll
        for (int jj = 0; jj < 4; ++jj) {
          unsigned int h[2], m[2], l[2];
          #pragma unroll
          for (int e = 0; e < 2; ++e) {
            float v = fmS[(cg * 8 + jj * 2 + e) * 128 + ty];
            split3(v, h[e], m[e], l[e]);
          }
          d0[jj] = h[0] | (h[1] << 16);
          d1[jj] = m[0] | (m[1] << 16);
          d2[jj] = l[0] | (l[1] << 16);
        }
        float* pp = pls + ty * 20 + cg * 4;
        *reinterpret_cast<uint4*>(pp)        = make_uint4(d0[0], d0[1], d0[2], d0[3]);
        *reinterpret_cast<uint4*>(pp + 2560) = make_uint4(d1[0], d1[1], d1[2], d1[3]);
        *reinterpret_cast<uint4*>(pp + 5120) = make_uint4(d2[0], d2[1], d2[2], d2[3]);
      }
      __syncthreads();
      #pragma unroll
      for (int yt = 0; yt < 4; ++yt) {
        const float* bp = pls + ((yc * 4 + yt) * 16 + ln) * 20 + kb * 4;
        bf16x8 B0 = *(const bf16x8*)(bp);
        bf16x8 B1 = *(const bf16x8*)(bp + 2560);
        bf16x8 B2 = *(const bf16x8*)(bp + 5120);
        #pragma unroll
        for (int ot = 0; ot < 2; ++ot)
          acc[ot][yt] = mfma6(af[ot][0], af[ot][1], af[ot][2], B0, B1, B2, acc[ot][yt]);
      }
    }

    for (int hh = 0; hh < 2; ++hh) {
      float u[16], se[4];
      #pragma unroll
      for (int i = 0; i < 16; ++i) u[i] = 0.0f;
      se[0] = se[1] = se[2] = se[3] = 0.0f;

      for (int hf = 0; hf < 2; ++hf) {
        if (wave == hh * 2 + hf) {
          #pragma unroll
          for (int ot = 0; ot < 2; ++ot)
            #pragma unroll
            for (int yt = 0; yt < 4; ++yt) {
              f32x4 a = acc[ot][yt];
              float4 p;
              p.x = __expf(a[0]); p.y = __expf(a[1]);
              p.z = __expf(a[2]); p.w = __expf(a[3]);
              *(float4*)(pb + (yt * 16 + ln) * 36 + ot * 16 + kb * 4) = p;
            }
        }
        if (wave == 4 + hh * 2 + hf) {
          #pragma unroll
          for (int yt = 0; yt < 4; ++yt) {
            f32x4 a0 = acc[0][yt], a1 = acc[1][yt];
            int yl = yt * 16 + ln;
            *(float4*)(vb + yl * 36 + kb * 4)      = make_float4(a0[0], a0[1], a0[2], a0[3]);
            *(float4*)(vb + yl * 36 + 16 + kb * 4) = make_float4(a1[0], a1[1], a1[2], a1[3]);
            float s = a0[0] * a0[0] + a0[1] * a0[1] + a0[2] * a0[2] + a0[3] * a0[3]
                    + a1[0] * a1[0] + a1[1] * a1[1] + a1[2] * a1[2] + a1[3] * a1[3];
            vss[kb * 64 + yl] = s;
          }
        }
        __syncthreads();
        if (t < 64) {
          float s2 = vss[t] + vss[64 + t] + vss[128 + t] + vss[192 + t];
          rnS[t] = 1.0f / fmaxf(sqrtf(s2), 1e-12f);
        }
        __syncthreads();
        #pragma unroll 2
        for (int yy = 0; yy < 8; ++yy) {
          int y = wave * 8 + yy;
          const float4 p = *(const float4*)(pb + y * 36 + dt * 4);
          float4 v = *(const float4*)(vb + y * 36 + et * 4);
          float rn = rnS[y];
          v.x *= rn; v.y *= rn; v.z *= rn; v.w *= rn;
          se[0] += p.x; se[1] += p.y; se[2] += p.z; se[3] += p.w;
          u[0]  = fmaf(p.x, v.x, u[0]);  u[1]  = fmaf(p.x, v.y, u[1]);
          u[2]  = fmaf(p.x, v.z, u[2]);  u[3]  = fmaf(p.x, v.w, u[3]);
          u[4]  = fmaf(p.y, v.x, u[4]);  u[5]  = fmaf(p.y, v.y, u[5]);
          u[6]  = fmaf(p.y, v.z, u[6]);  u[7]  = fmaf(p.y, v.w, u[7]);
          u[8]  = fmaf(p.z, v.x, u[8]);  u[9]  = fmaf(p.z, v.y, u[9]);
          u[10] = fmaf(p.z, v.z, u[10]); u[11] = fmaf(p.z, v.w, u[11]);
          u[12] = fmaf(p.w, v.x, u[12]); u[13] = fmaf(p.w, v.y, u[13]);
          u[14] = fmaf(p.w, v.z, u[14]); u[15] = fmaf(p.w, v.w, u[15]);
        }
        __syncthreads();
      }
      *(float4*)(red + t * 16 + 0)  = make_float4(u[0], u[1], u[2], u[3]);
      *(float4*)(red + t * 16 + 4)  = make_float4(u[4], u[5], u[6], u[7]);
      *(float4*)(red + t * 16 + 8)  = make_float4(u[8], u[9], u[10], u[11]);
      *(float4*)(red + t * 16 + 12) = make_float4(u[12], u[13], u[14], u[15]);
      if (et == 0)
        *(float4*)(ser + (wave * 8 + dt) * 4) = make_float4(se[0], se[1], se[2], se[3]);
      __syncthreads();
      {
        const int tile = t >> 3;
        const int i0 = (t & 7) * 2;
        float s0 = 0.0f, s1 = 0.0f;
        #pragma unroll
        for (int w = 0; w < 8; ++w) {
          s0 += red[(w * 64 + tile) * 16 + i0];
          s1 += red[(w * 64 + tile) * 16 + i0 + 1];
        }
        const int d = (tile >> 3) * 4 + (i0 >> 2);
        const int e = (tile & 7) * 4 + (i0 & 3);
        float* ca = ws + OFF_CTXA + ((size_t)(b * 8 + blk * 2 + hh) * 16 + xg) * 1056;
        atomicAdd(ca + d * 32 + e, s0);
        atomicAdd(ca + d * 32 + e + 1, s1);
        if (t < 32) {
          float ss = 0.0f;
          #pragma unroll
          for (int w = 0; w < 8; ++w) ss += ser[(w * 8 + (t >> 2)) * 4 + (t & 3)];
          atomicAdd(ca + 1024 + t, ss);
        }
      }
    }
  }
}

// ---------------- reduce x-group partials, fold scales, emit sigma-permuted bf16 planes ----------------
__global__ void ctx_reduce_kernel(float* __restrict__ ws) {
  __shared__ float sume[32];
  const int bh = blockIdx.x, t = threadIdx.x;
  const float* ca = ws + OFF_CTXA + (size_t)bh * 16 * 1056;
  if (t < 32) {
    double a = 0.0;
    #pragma unroll
    for (int xg = 0; xg < 16; ++xg) a += ca[xg * 1056 + 1024 + t];
    sume[t] = (float)a;
  }
  __syncthreads();
  const double sb = (1.0 / 16384.0) * 0.17677669529663688;  // inv^2 * dh^-0.5
  unsigned short* cp = (unsigned short*)(ws + OFF_CTXP) + (size_t)bh * 3072;
  #pragma unroll
  for (int i = 0; i < 4; ++i) {
    int de = t + 256 * i;
    int d = de >> 5, e = de & 31;
    double a = 0.0;
    #pragma unroll
    for (int xg = 0; xg < 16; ++xg) a += ca[xg * 1056 + de];
    float v = (float)(a * sb / (double)sume[d]);
    // sigma: k = kb*8 + ot*4 + r with d = ot*16 + kb*4 + r
    int k = ((d >> 2) & 3) * 8 + ((d >> 4) & 1) * 4 + (d & 3);
    unsigned h, m, l;
    split3(v, h, m, l);
    cp[e * 32 + k]        = (unsigned short)h;
    cp[1024 + e * 32 + k] = (unsigned short)m;
    cp[2048 + e * 32 + k] = (unsigned short)l;
  }
}

// ---------------- final v5: (512,2) = 256 regs/lane, spill-free; R3 qctx structure ----------------
// LDS floats: staging fmS[32][128]@0 + pls 3x[128][20]@4096 (11776); gel planes 3x[128][36]@0
// (13824, alias staging); muS@13824,rsS,g0S,b0S, lnm@14336, lnr@14464 -> 14592 floats = 58.4 KB
__launch_bounds__(512, 2)
__global__ void final_kernel(const float* __restrict__ fmap,
                             const float* __restrict__ g0,
                             const float* __restrict__ b0,
                             const float* __restrict__ g1,
                             const float* __restrict__ b1,
                             const float* __restrict__ ws,
                             float* __restrict__ out) {
  __shared__ float sm[14592];
  const int x = blockIdx.x, b = blockIdx.y, t = threadIdx.x;
  const int wave = t >> 6, lane = t & 63;
  const int ln = lane & 15, kb = lane >> 4;   // MFMA fragment coords
  const int or2 = wave >> 1, yc = wave & 1;   // wave tile: o-tiles(or head) x y-halves

  float* fmS = sm;            // [32][128] staging
  float* pls = sm + 4096;     // 3 planes x [128][20] staging splits
  float* gel = sm;            // 3 planes x [128][36] gel splits (aliases staging)
  float* muS = sm + 13824;
  float* rsS = sm + 13952;
  float* g0S = sm + 14080;
  float* b0S = sm + 14208;
  float* lnm = sm + 14336;
  float* lnr = sm + 14464;

  if (t < 128) {
    muS[t] = ws[OFF_MU + (unsigned)((b * 128 + t) * 128 + x)];
    rsS[t] = ws[OFF_RSTD + (unsigned)((b * 128 + t) * 128 + x)];
  } else if (t < 256) g0S[t - 128] = g0[t - 128];
  else if (t < 384) b0S[t - 256] = b0[t - 256];

  const unsigned short* wqspl = (const unsigned short*)(ws + OFF_WQSPL);
  const unsigned short* wospl = (const unsigned short*)(ws + OFF_WOSPL);
  const unsigned short* ctxp  = (const unsigned short*)(ws + OFF_CTXP);

  f32x4 oacc[2][4];
  #pragma unroll
  for (int i = 0; i < 2; ++i)
    #pragma unroll
    for (int j = 0; j < 4; ++j) oacc[i][j] = (f32x4){0.f, 0.f, 0.f, 0.f};

  for (int qblk = 0; qblk < 2; ++qblk) {
    f32x4 qacc[2][4];
    #pragma unroll
    for (int i = 0; i < 2; ++i)
      #pragma unroll
      for (int j = 0; j < 4; ++j) qacc[i][j] = (f32x4){0.f, 0.f, 0.f, 0.f};

    // ---- Q matmul over 4 c-chunks ----
    for (int cc = 0; cc < 4; ++cc) {
      bf16x8 af[2][3];
      #pragma unroll
      for (int ot = 0; ot < 2; ++ot)
        #pragma unroll
        for (int p = 0; p < 3; ++p)
          af[ot][p] = *(const bf16x8*)(wqspl + p * 32768 +
              ((qblk * 128 + or2 * 32 + ot * 16 + ln) * 128 + cc * 32 + kb * 8));

      __syncthreads();                          // staging region free of prior readers
      #pragma unroll
      for (int it = 0; it < 2; ++it) {          // stage fm chunk, LN0 applied (f32)
        int idx4 = it * 512 + t;
        int c = idx4 >> 5, y4 = (idx4 & 31) * 4;
        int cg = cc * 32 + c;
        const float4 r = *(const float4*)(fmap + (((size_t)(b * 128 + cg)) * 128 + x) * 128 + y4);
        float mu = muS[cg], rs = rsS[cg];
        float4 g = *(const float4*)(g0S + y4);
        float4 be = *(const float4*)(b0S + y4);
        float4 o;
        o.x = (r.x - mu) * rs * g.x + be.x;
        o.y = (r.y - mu) * rs * g.y + be.y;
        o.z = (r.z - mu) * rs * g.z + be.z;
        o.w = (r.w - mu) * rs * g.w + be.w;
        *(float4*)(fmS + c * 128 + y4) = o;
      }
      __syncthreads();
      {                                         // transpose + 3-way bf16 split
        const int ty = t & 127, cg = t >> 7;
        unsigned int d0[4], d1[4], d2[4];
        #pragma unroll
        for (int jj = 0; jj < 4; ++jj) {
          unsigned int h[2], m[2], l[2];
          #pragma unroll
          for (int e = 0; e < 2; ++e) {
            float v = fmS[(cg * 8 + jj * 2 + e) * 128 + ty];
            split3(v, h[e], m[e], l[e]);
          }
          d0[jj] = h[0] | (h[1] << 16);
          d1[jj] = m[0] | (m[1] << 16);
          d2[jj] = l[0] | (l[1] << 16);
        }
        float* pp = pls + ty * 20 + cg * 4;
        *reinterpret_cast<uint4*>(pp)        = make_uint4(d0[0], d0[1], d0[2], d0[3]);
        *reinterpret_cast<uint4*>(pp + 2560) = make_uint4(d1[0], d1[1], d1[2], d1[3]);
        *reinterpret_cast<uint4*>(pp + 5120) = make_uint4(d2[0], d2[1], d2[2], d2[3]);
      }
      __syncthreads();
      #pragma unroll
      for (int yt = 0; yt < 4; ++yt) {
        const float* bp = pls + ((yc * 4 + yt) * 16 + ln) * 20 + kb * 4;
        bf16x8 B0 = *(const bf16x8*)(bp);
        bf16x8 B1 = *(const bf16x8*)(bp + 2560);
        bf16x8 B2 = *(const bf16x8*)(bp + 5120);
        #pragma unroll
        for (int ot = 0; ot < 2; ++ot)
          qacc[ot][yt] = mfma6(af[ot][0], af[ot][1], af[ot][2], B0, B1, B2, qacc[ot][yt]);
      }
    }

    // ---- in-register exp + ssum (4-lane butterfly) + 3-split pack (sigma layout) ----
    // lane holds d = ot*16+kb*4+r at y = (yc*4+yt)*16+ln; B-frag k = kb*8+ot*4+r == own values
    float rssum[4];
    bf16x8 pf0[4], pf1[4], pf2[4];
    #pragma unroll
    for (int yt = 0; yt < 4; ++yt) {
      float pv[8];
      #pragma unroll
      for (int ot = 0; ot < 2; ++ot)
        #pragma unroll
        for (int r = 0; r < 4; ++r)
          pv[ot * 4 + r] = __expf(qacc[ot][yt][r]);
      float ps = ((pv[0] + pv[1]) + (pv[2] + pv[3])) + ((pv[4] + pv[5]) + (pv[6] + pv[7]));
      ps += __shfl_xor(ps, 16);
      ps += __shfl_xor(ps, 32);
      rssum[yt] = 1.0f / ps;
      unsigned wh[4], wm[4], wl[4];
      #pragma unroll
      for (int j = 0; j < 4; ++j) {
        unsigned h0, m0, l0, h1, m1, l1;
        split3(pv[2 * j], h0, m0, l0);
        split3(pv[2 * j + 1], h1, m1, l1);
        wh[j] = h0 | (h1 << 16);
        wm[j] = m0 | (m1 << 16);
        wl[j] = l0 | (l1 << 16);
      }
      uint4 uh = make_uint4(wh[0], wh[1], wh[2], wh[3]);
      uint4 um = make_uint4(wm[0], wm[1], wm[2], wm[3]);
      uint4 ul = make_uint4(wl[0], wl[1], wl[2], wl[3]);
      pf0[yt] = *(const bf16x8*)&uh;
      pf1[yt] = *(const bf16x8*)&um;
      pf2[yt] = *(const bf16x8*)&ul;
    }

    // ---- ge[e][y] = sum_d ctx[d][e] * exp(q[d][y]) via MFMA (A from L2, B in-reg) ----
    f32x4 ge[2][4];
    const unsigned short* chp = ctxp + (size_t)(b * 8 + qblk * 4 + or2) * 3072;
    #pragma unroll
    for (int ot = 0; ot < 2; ++ot) {
      bf16x8 aq0 = *(const bf16x8*)(chp +        (ot * 16 + ln) * 32 + kb * 8);
      bf16x8 aq1 = *(const bf16x8*)(chp + 1024 + (ot * 16 + ln) * 32 + kb * 8);
      bf16x8 aq2 = *(const bf16x8*)(chp + 2048 + (ot * 16 + ln) * 32 + kb * 8);
      #pragma unroll
      for (int yt = 0; yt < 4; ++yt) {
        f32x4 c = (f32x4){0.f, 0.f, 0.f, 0.f};
        ge[ot][yt] = mfma6(aq0, aq1, aq2, pf0[yt], pf1[yt], pf2[yt], c);
      }
    }

    // ---- gelu in-register (ge layout: e = ot*16+kb*4+r, y = (yc*4+yt)*16+ln) ----
    #pragma unroll
    for (int ot = 0; ot < 2; ++ot)
      #pragma unroll
      for (int yt = 0; yt < 4; ++yt)
        #pragma unroll
        for (int r = 0; r < 4; ++r) {
          float v = ge[ot][yt][r] * rssum[yt];
          ge[ot][yt][r] = 0.5f * v * (1.0f + erff(v * 0.70710678118654752f));
        }

    // ---- out-conv in 2 phases of K=64 (heads {2ph, 2ph+1}) ----
    for (int ph = 0; ph < 2; ++ph) {
      __syncthreads();                          // prior readers of gel region done
      if ((or2 >> 1) == ph) {                   // this wave's head is in the chunk
        const int c16 = (or2 & 1) * 16;
        #pragma unroll
        for (int yt = 0; yt < 4; ++yt) {
          float* grow = gel + ((yc * 4 + yt) * 16 + ln) * 36 + c16 + kb * 4;
          #pragma unroll
          for (int ot = 0; ot < 2; ++ot) {
            unsigned h0, m0, l0, h1, m1, l1, h2, m2, l2, h3, m3, l3;
            split3(ge[ot][yt][0], h0, m0, l0);
            split3(ge[ot][yt][1], h1, m1, l1);
            split3(ge[ot][yt][2], h2, m2, l2);
            split3(ge[ot][yt][3], h3, m3, l3);
            *(uint2*)(grow + ot * 2)        = make_uint2(h0 | (h1 << 16), h2 | (h3 << 16));
            *(uint2*)(grow + 4608 + ot * 2) = make_uint2(m0 | (m1 << 16), m2 | (m3 << 16));
            *(uint2*)(grow + 9216 + ot * 2) = make_uint2(l0 | (l1 << 16), l2 | (l3 << 16));
          }
        }
      }
      __syncthreads();                          // gel planes visible
      #pragma unroll
      for (int kc = 0; kc < 2; ++kc) {
        bf16x8 ao[2][3];
        #pragma unroll
        for (int ot = 0; ot < 2; ++ot)
          #pragma unroll
          for (int p = 0; p < 3; ++p)
            ao[ot][p] = *(const bf16x8*)(wospl + p * 32768 +
                ((or2 * 32 + ot * 16 + ln) * 256 + qblk * 128 + ph * 64 + kc * 32 + kb * 8));
        #pragma unroll
        for (int yt = 0; yt < 4; ++yt) {
          const float* bp = gel + ((yc * 4 + yt) * 16 + ln) * 36 + kc * 16 + kb * 4;
          bf16x8 B0 = *(const bf16x8*)(bp);
          bf16x8 B1 = *(const bf16x8*)(bp + 4608);
          bf16x8 B2 = *(const bf16x8*)(bp + 9216);
          #pragma unroll
          for (int ot = 0; ot < 2; ++ot)
            oacc[ot][yt] = mfma6(ao[ot][0], ao[ot][1], ao[ot][2], B0, B1, B2, oacc[ot][yt]);
        }
      }
    }
  }

  // ---- LN1 over y per o-row (acc layout: o = or2*32+ot*16+kb*4+r, y = (yc*4+yt)*16+ln) ----
  __syncthreads();
  float* red_s = sm;
  float* red_q = sm + 4096;
  #pragma unroll
  for (int ot = 0; ot < 2; ++ot)
    #pragma unroll
    for (int r = 0; r < 4; ++r) {
      int o = or2 * 32 + ot * 16 + kb * 4 + r;
      float s = 0.0f, q = 0.0f;
      #pragma unroll
      for (int yt = 0; yt < 4; ++yt) { float v = oacc[ot][yt][r]; s += v; q = fmaf(v, v, q); }
      red_s[o * 32 + yc * 16 + ln] = s;
      red_q[o * 32 + yc * 16 + ln] = q;
    }
  __syncthreads();
  if (t < 128) {
    double s = 0.0, q = 0.0;
    #pragma unroll
    for (int i = 0; i < 32; ++i) { s += red_s[t * 32 + i]; q += red_q[t * 32 + i]; }
    double mu = s * (1.0 / 128.0);
    double var = q * (1.0 / 128.0) - mu * mu;
    lnm[t] = (float)mu;
    lnr[t] = (float)(1.0 / sqrt(var + 1e-5));
  }
  __syncthreads();
  float g1v[4], b1v[4];
  #pragma unroll
  for (int yt = 0; yt < 4; ++yt) {
    int y = (yc * 4 + yt) * 16 + ln;
    g1v[yt] = g1[y]; b1v[yt] = b1[y];
  }
  #pragma unroll
  for (int ot = 0; ot < 2; ++ot)
    #pragma unroll
    for (int r = 0; r < 4; ++r) {
      int o = or2 * 32 + ot * 16 + kb * 4 + r;
      float mu = lnm[o], rs = lnr[o];
      #pragma unroll
      for (int yt = 0; yt < 4; ++yt) {
        int y = (yc * 4 + yt) * 16 + ln;
        out[(((size_t)(b * 128 + o)) * 128 + x) * 128 + y] =
            (oacc[ot][yt][r] - mu) * rs * g1v[yt] + b1v[yt];
      }
    }
}

extern "C" void kernel_launch(void* const* d_in, const int* in_sizes, int n_in,
                              void* d_out, int out_size, void* d_ws, size_t ws_size,
                              hipStream_t stream) {
  const float* fmap = (const float*)d_in[0];
  const float* g0   = (const float*)d_in[1];
  const float* b0   = (const float*)d_in[2];
  const float* wqkv = (const float*)d_in[3];
  const float* wout = (const float*)d_in[4];
  const float* g1   = (const float*)d_in[5];
  const float* b1   = (const float*)d_in[6];
  float* ws  = (float*)d_ws;
  float* out = (float*)d_out;

  hipMemsetAsync((char*)d_ws + (size_t)OFF_CTXA * 4, 0, (size_t)2162688 * 4, stream);
  prep_kernel<<<512, 256, 0, stream>>>(wqkv, wout, ws);
  kv_ctx_kernel<<<dim3(128, 16), 512, 0, stream>>>(fmap, g0, b0, ws);
  ctx_reduce_kernel<<<128, 256, 0, stream>>>(ws);
  final_kernel<<<dim3(128, 16), 512, 0, stream>>>(fmap, g0, b0, g1, b1, ws, out);
}

// Round 6
// 872.333 us; speedup vs baseline: 1.5466x; 1.0132x over previous
//
#include <hip/hip_runtime.h>
#include <math.h>

// B=16, C=128, X=128, Y=128, heads=8, dh=32, inner=256
// ws layout (float offsets):
#define OFF_MU    0u          // [262144] per (b,c,x)
#define OFF_RSTD  262144u
#define OFF_CTXA  524288u     // [bh=128][xg=16][1056] atomic partials (U 1024 + sexp 32)
#define OFF_CTXP  2686976u    // sigma-permuted ctx: [bh=128][3 planes][32 e][32 k] bf16 (3072 shorts/bh)
#define OFF_WSPL  2883584u    // 3 bf16 planes of permuted k/v weights (65536 shorts/plane)
#define OFF_WQSPL 2981888u    // 3 bf16 planes of q weights [256 o][128 c] (32768 shorts/plane)
#define OFF_WOSPL 3031040u    // 3 bf16 planes of wout [128 o][256 k-sigma] (32768 shorts/plane)
                              // end: 3080192 floats = 12.32 MB

typedef __attribute__((ext_vector_type(8))) short bf16x8;
typedef __attribute__((ext_vector_type(4))) float f32x4;

__device__ __forceinline__ void split3(float v, unsigned& h, unsigned& m, unsigned& l) {
  unsigned u = __float_as_uint(v);
  float r1 = v - __uint_as_float(u & 0xffff0000u);
  unsigned u1 = __float_as_uint(r1);
  float r2 = r1 - __uint_as_float(u1 & 0xffff0000u);
  h = u >> 16; m = u1 >> 16; l = __float_as_uint(r2) >> 16;
}

// 6-product split-bf16 MFMA: A,B are 3-plane splits (h,m,l)
__device__ __forceinline__ f32x4 mfma6(const bf16x8& A0, const bf16x8& A1, const bf16x8& A2,
                                       const bf16x8& B0, const bf16x8& B1, const bf16x8& B2,
                                       f32x4 c) {
  c = __builtin_amdgcn_mfma_f32_16x16x32_bf16(A0, B0, c, 0, 0, 0);
  c = __builtin_amdgcn_mfma_f32_16x16x32_bf16(A0, B1, c, 0, 0, 0);
  c = __builtin_amdgcn_mfma_f32_16x16x32_bf16(A1, B0, c, 0, 0, 0);
  c = __builtin_amdgcn_mfma_f32_16x16x32_bf16(A0, B2, c, 0, 0, 0);
  c = __builtin_amdgcn_mfma_f32_16x16x32_bf16(A1, B1, c, 0, 0, 0);
  c = __builtin_amdgcn_mfma_f32_16x16x32_bf16(A2, B0, c, 0, 0, 0);
  return c;
}

// ---------------- prep: bf16 3-way weight splits ----------------
__global__ void prep_kernel(const float* __restrict__ wqkv,
                            const float* __restrict__ wout,
                            float* __restrict__ ws) {
  int idx = blockIdx.x * 256 + threadIdx.x;   // 512 blocks -> 131072
  float v;
  unsigned short* wp;
  unsigned plane, slot;
  if (idx < 65536) {
    // k/v weight rows, permuted per-blk
    int row = idx >> 7, c = idx & 127;   // row 0..511
    int blk = row >> 7, ol = row & 127;
    int hh = (ol >> 5) & 1;
    int src = ((ol & 64) ? 512 : 256) + (2 * blk + hh) * 32 + (ol & 31);
    v = wqkv[src * 128 + c];
    wp = (unsigned short*)(ws + OFF_WSPL);
    plane = 65536; slot = (unsigned)idx;
  } else if (idx < 98304) {
    // q weights: rows o=0..255 of wqkv, layout [o][c]
    int j = idx - 65536;
    v = wqkv[j];
    wp = (unsigned short*)(ws + OFF_WQSPL);
    plane = 32768; slot = (unsigned)j;
  } else {
    // wout sigma-permuted: dst slot [o][k], src cp within each 32-chunk:
    // k = kb*8+ot*4+r  <->  cp = ot*16+kb*4+r
    int j = idx - 98304;
    int o = j >> 8, k = j & 255;
    int cp = (k & 0xE0) | (((k >> 2) & 1) << 4) | (((k >> 3) & 3) << 2) | (k & 3);
    v = wout[o * 256 + cp];
    wp = (unsigned short*)(ws + OFF_WOSPL);
    plane = 32768; slot = (unsigned)j;
  }
  unsigned h, m, l;
  split3(v, h, m, l);
  wp[slot]             = (unsigned short)h;
  wp[plane + slot]     = (unsigned short)m;
  wp[2 * plane + slot] = (unsigned short)l;
}

// ---------------- K1 v2: LN0 stats + single-pass staging (all 4 blks) + merged epilogue ----------------
// (512,2): 256 regs/lane. acc[4][2][4]=128 AGPRs; fm staged/split ONCE per block.
// LDS (floats): staging fmS[32][128]@0 + pls 3x[128][20]@4096 -> 11776; muS@11776,rsS,g0S,b0S -> 12288.
// epilogue (aliases staging): pb[2][128][36]@0, vb[2][128][36]@9216, vss[2][4][128]@18432,
// rnS[2][128]@19456, ser[2][4][8][4]@19712 -> 19968 floats = 78 KB; red[2][4][64][16]@0 aliases pb.
__launch_bounds__(512, 2)
__global__ void kv_ctx_kernel(const float* __restrict__ fmap,
                              const float* __restrict__ g0,
                              const float* __restrict__ b0,
                              float* __restrict__ ws) {
  __shared__ float sm[19968];
  const int x = blockIdx.x, b = blockIdx.y, t = threadIdx.x;
  const int wave = t >> 6, lane = t & 63;
  const int ln = lane & 15, kb = lane >> 4;
  const int or2 = wave >> 1, yc = wave & 1;
  const int dt = lane >> 3, et = lane & 7;
  const int xg = x >> 3;

  float* fmS = sm;             // [32][128] staging
  float* pls = sm + 4096;      // 3 planes x [128 y][20 dw]
  float* muS = sm + 11776;
  float* rsS = sm + 11904;
  float* g0S = sm + 12032;
  float* b0S = sm + 12160;
  float* pb  = sm;             // [2 h][128 y][36] exp(k)  (epilogue, aliases staging)
  float* vb  = sm + 9216;      // [2 h][128 y][36] raw v
  float* vss = sm + 18432;     // [2 h][4 kb][128 y]
  float* rnS = sm + 19456;     // [2 h][128 y]
  float* ser = sm + 19712;     // [2 h][4 w4][8 dt][4]
  float* red = sm;             // [2 h][4 w4][64 tile][16] (aliases pb)

  // ---- LN0 stats for this (b,x) ----
  {
    const int r = t >> 2, q = t & 3;          // row c = r, y-quarter q
    const float* p = fmap + (((size_t)(b * 128 + r)) * 128 + x) * 128 + q * 32;
    double s = 0.0, qq = 0.0;
    #pragma unroll
    for (int i = 0; i < 8; ++i) {
      float4 v4 = *(const float4*)(p + i * 4);
      s  += (double)v4.x + (double)v4.y + (double)v4.z + (double)v4.w;
      qq += (double)v4.x * v4.x + (double)v4.y * v4.y
          + (double)v4.z * v4.z + (double)v4.w * v4.w;
    }
    s += __shfl_xor(s, 1); qq += __shfl_xor(qq, 1);
    s += __shfl_xor(s, 2); qq += __shfl_xor(qq, 2);
    if (q == 0) {
      double mu = s * (1.0 / 128.0);
      double var = qq * (1.0 / 128.0) - mu * mu;
      float muf = (float)mu, rsf = (float)(1.0 / sqrt(var + 1e-5));
      muS[r] = muf; rsS[r] = rsf;
      ws[OFF_MU + (unsigned)((b * 128 + r) * 128 + x)] = muf;
      ws[OFF_RSTD + (unsigned)((b * 128 + r) * 128 + x)] = rsf;
    }
  }
  if (t < 128) { g0S[t] = g0[t]; b0S[t] = b0[t]; }

  const unsigned short* wspl = (const unsigned short*)(ws + OFF_WSPL);

  f32x4 acc[4][2][4];
  #pragma unroll
  for (int k = 0; k < 4; ++k)
    #pragma unroll
    for (int i = 0; i < 2; ++i)
      #pragma unroll
      for (int j = 0; j < 4; ++j) acc[k][i][j] = (f32x4){0.f, 0.f, 0.f, 0.f};

  // ---- single staging pass over 4 c-chunks; MFMA for all 4 blks per chunk ----
  for (int cc = 0; cc < 4; ++cc) {
    __syncthreads();                          // pls readers of prev cc done
    #pragma unroll
    for (int it = 0; it < 2; ++it) {          // stage fm chunk, LN0 applied (f32)
      int idx4 = it * 512 + t;
      int c = idx4 >> 5, y4 = (idx4 & 31) * 4;
      int cg = cc * 32 + c;
      const float4 r = *(const float4*)(fmap + (((size_t)(b * 128 + cg)) * 128 + x) * 128 + y4);
      float mu = muS[cg], rs = rsS[cg];
      float4 g = *(const float4*)(g0S + y4);
      float4 be = *(const float4*)(b0S + y4);
      float4 o;
      o.x = (r.x - mu) * rs * g.x + be.x;
      o.y = (r.y - mu) * rs * g.y + be.y;
      o.z = (r.z - mu) * rs * g.z + be.z;
      o.w = (r.w - mu) * rs * g.w + be.w;
      *(float4*)(fmS + c * 128 + y4) = o;
    }
    __syncthreads();
    {                                         // transpose + 3-way bf16 split
      const int ty = t & 127, cg = t >> 7;
      unsigned int d0[4], d1[4], d2[4];
      #pragma unroll
      for (int jj = 0; jj < 4; ++jj) {
        unsigned int h[2], m[2], l[2];
        #pragma unroll
        for (int e = 0; e < 2; ++e) {
          float v = fmS[(cg * 8 + jj * 2 + e) * 128 + ty];
          split3(v, h[e], m[e], l[e]);
        }
        d0[jj] = h[0] | (h[1] << 16);
        d1[jj] = m[0] | (m[1] << 16);
        d2[jj] = l[0] | (l[1] << 16);
      }
      float* pp = pls + ty * 20 + cg * 4;
      *reinterpret_cast<uint4*>(pp)        = make_uint4(d0[0], d0[1], d0[2], d0[3]);
      *reinterpret_cast<uint4*>(pp + 2560) = make_uint4(d1[0], d1[1], d1[2], d1[3]);
      *reinterpret_cast<uint4*>(pp + 5120) = make_uint4(d2[0], d2[1], d2[2], d2[3]);
    }
    __syncthreads();
    #pragma unroll
    for (int pg = 0; pg < 2; ++pg) {          // blk pairs {0,1},{2,3}: af 48 regs live
      bf16x8 af[2][2][3];
      #pragma unroll
      for (int bb = 0; bb < 2; ++bb)
        #pragma unroll
        for (int ot = 0; ot < 2; ++ot)
          #pragma unroll
          for (int p = 0; p < 3; ++p)
            af[bb][ot][p] = *(const bf16x8*)(wspl + p * 65536 +
                (((pg * 2 + bb) * 128 + or2 * 32 + ot * 16 + ln) * 128 + cc * 32 + kb * 8));
      #pragma unroll
      for (int yt = 0; yt < 4; ++yt) {
        const float* bp = pls + ((yc * 4 + yt) * 16 + ln) * 20 + kb * 4;
        bf16x8 B0 = *(const bf16x8*)(bp);
        bf16x8 B1 = *(const bf16x8*)(bp + 2560);
        bf16x8 B2 = *(const bf16x8*)(bp + 5120);
        #pragma unroll
        for (int bb = 0; bb < 2; ++bb)
          #pragma unroll
          for (int ot = 0; ot < 2; ++ot)
            acc[pg * 2 + bb][ot][yt] =
                mfma6(af[bb][ot][0], af[bb][ot][1], af[bb][ot][2], B0, B1, B2,
                      acc[pg * 2 + bb][ot][yt]);
      }
    }
  }

  // ---- epilogue: per blk, both heads processed by all 8 waves ----
  #pragma unroll
  for (int blk = 0; blk < 4; ++blk) {
    __syncthreads();                          // staging readers / prev reduce readers done
    if (or2 < 2) {                            // k waves: head h = or2, exp -> pb[h][y][d]
      const int h = or2;
      #pragma unroll
      for (int ot = 0; ot < 2; ++ot)
        #pragma unroll
        for (int yt = 0; yt < 4; ++yt) {
          f32x4 a = acc[blk][ot][yt];
          float4 p;
          p.x = __expf(a[0]); p.y = __expf(a[1]);
          p.z = __expf(a[2]); p.w = __expf(a[3]);
          *(float4*)(pb + h * 4608 + ((yc * 4 + yt) * 16 + ln) * 36 + ot * 16 + kb * 4) = p;
        }
    } else {                                  // v waves: head h = or2-2, raw v + sumsq
      const int h = or2 - 2;
      #pragma unroll
      for (int yt = 0; yt < 4; ++yt) {
        f32x4 a0 = acc[blk][0][yt], a1 = acc[blk][1][yt];
        int y = (yc * 4 + yt) * 16 + ln;
        *(float4*)(vb + h * 4608 + y * 36 + kb * 4)      = make_float4(a0[0], a0[1], a0[2], a0[3]);
        *(float4*)(vb + h * 4608 + y * 36 + 16 + kb * 4) = make_float4(a1[0], a1[1], a1[2], a1[3]);
        float s = a0[0] * a0[0] + a0[1] * a0[1] + a0[2] * a0[2] + a0[3] * a0[3]
                + a1[0] * a1[0] + a1[1] * a1[1] + a1[2] * a1[2] + a1[3] * a1[3];
        vss[h * 512 + kb * 128 + y] = s;
      }
    }
    __syncthreads();
    if (t < 256) {                            // rn per (h, y)
      int h = t >> 7, y = t & 127;
      const float* vh = vss + h * 512;
      float s2 = vh[y] + vh[128 + y] + vh[256 + y] + vh[384 + y];
      rnS[h * 128 + y] = 1.0f / fmaxf(sqrtf(s2), 1e-12f);
    }
    __syncthreads();
    float u[16], se[4];
    #pragma unroll
    for (int i = 0; i < 16; ++i) u[i] = 0.0f;
    se[0] = se[1] = se[2] = se[3] = 0.0f;
    {                                         // U tile: head = wave>>2, y-slice = (wave&3)*32
      const int h = wave >> 2, yb = (wave & 3) * 32;
      const float* pbh = pb + h * 4608;
      const float* vbh = vb + h * 4608;
      const float* rnh = rnS + h * 128;
      #pragma unroll 4
      for (int yy = 0; yy < 32; ++yy) {
        int y = yb + yy;
        const float4 p = *(const float4*)(pbh + y * 36 + dt * 4);
        float4 v = *(const float4*)(vbh + y * 36 + et * 4);
        float rn = rnh[y];
        v.x *= rn; v.y *= rn; v.z *= rn; v.w *= rn;
        se[0] += p.x; se[1] += p.y; se[2] += p.z; se[3] += p.w;
        u[0]  = fmaf(p.x, v.x, u[0]);  u[1]  = fmaf(p.x, v.y, u[1]);
        u[2]  = fmaf(p.x, v.z, u[2]);  u[3]  = fmaf(p.x, v.w, u[3]);
        u[4]  = fmaf(p.y, v.x, u[4]);  u[5]  = fmaf(p.y, v.y, u[5]);
        u[6]  = fmaf(p.y, v.z, u[6]);  u[7]  = fmaf(p.y, v.w, u[7]);
        u[8]  = fmaf(p.z, v.x, u[8]);  u[9]  = fmaf(p.z, v.y, u[9]);
        u[10] = fmaf(p.z, v.z, u[10]); u[11] = fmaf(p.z, v.w, u[11]);
        u[12] = fmaf(p.w, v.x, u[12]); u[13] = fmaf(p.w, v.y, u[13]);
        u[14] = fmaf(p.w, v.z, u[14]); u[15] = fmaf(p.w, v.w, u[15]);
      }
    }
    __syncthreads();                          // pb reads done; red may clobber
    {
      const int h = wave >> 2;
      float* rp = red + h * 4096 + ((wave & 3) * 64 + lane) * 16;
      *(float4*)(rp + 0)  = make_float4(u[0], u[1], u[2], u[3]);
      *(float4*)(rp + 4)  = make_float4(u[4], u[5], u[6], u[7]);
      *(float4*)(rp + 8)  = make_float4(u[8], u[9], u[10], u[11]);
      *(float4*)(rp + 12) = make_float4(u[12], u[13], u[14], u[15]);
      if (et == 0)
        *(float4*)(ser + h * 128 + ((wave & 3) * 8 + dt) * 4) = make_float4(se[0], se[1], se[2], se[3]);
    }
    __syncthreads();
    {                                         // reduce 4 wave-partials, atomics to CTXA
      const int tile = t >> 3, i0 = (t & 7) * 2;
      const int d = (tile >> 3) * 4 + (i0 >> 2);
      const int e = (tile & 7) * 4 + (i0 & 3);
      #pragma unroll
      for (int h = 0; h < 2; ++h) {
        const float* rh = red + h * 4096;
        float s0 = 0.0f, s1 = 0.0f;
        #pragma unroll
        for (int w4 = 0; w4 < 4; ++w4) {
          s0 += rh[(w4 * 64 + tile) * 16 + i0];
          s1 += rh[(w4 * 64 + tile) * 16 + i0 + 1];
        }
        float* ca = ws + OFF_CTXA + ((size_t)(b * 8 + blk * 2 + h) * 16 + xg) * 1056;
        atomicAdd(ca + d * 32 + e, s0);
        atomicAdd(ca + d * 32 + e + 1, s1);
      }
      if (t < 64) {
        int h = t >> 5, tq = t & 31;
        float ss = 0.0f;
        #pragma unroll
        for (int w4 = 0; w4 < 4; ++w4)
          ss += ser[h * 128 + (w4 * 8 + (tq >> 2)) * 4 + (tq & 3)];
        float* ca = ws + OFF_CTXA + ((size_t)(b * 8 + blk * 2 + h) * 16 + xg) * 1056;
        atomicAdd(ca + 1024 + tq, ss);
      }
    }
  }
}

// ---------------- reduce x-group partials, fold scales, emit sigma-permuted bf16 planes ----------------
__global__ void ctx_reduce_kernel(float* __restrict__ ws) {
  __shared__ float sume[32];
  const int bh = blockIdx.x, t = threadIdx.x;
  const float* ca = ws + OFF_CTXA + (size_t)bh * 16 * 1056;
  if (t < 32) {
    double a = 0.0;
    #pragma unroll
    for (int xg = 0; xg < 16; ++xg) a += ca[xg * 1056 + 1024 + t];
    sume[t] = (float)a;
  }
  __syncthreads();
  const double sb = (1.0 / 16384.0) * 0.17677669529663688;  // inv^2 * dh^-0.5
  unsigned short* cp = (unsigned short*)(ws + OFF_CTXP) + (size_t)bh * 3072;
  #pragma unroll
  for (int i = 0; i < 4; ++i) {
    int de = t + 256 * i;
    int d = de >> 5, e = de & 31;
    double a = 0.0;
    #pragma unroll
    for (int xg = 0; xg < 16; ++xg) a += ca[xg * 1056 + de];
    float v = (float)(a * sb / (double)sume[d]);
    // sigma: k = kb*8 + ot*4 + r with d = ot*16 + kb*4 + r
    int k = ((d >> 2) & 3) * 8 + ((d >> 4) & 1) * 4 + (d & 3);
    unsigned h, m, l;
    split3(v, h, m, l);
    cp[e * 32 + k]        = (unsigned short)h;
    cp[1024 + e * 32 + k] = (unsigned short)m;
    cp[2048 + e * 32 + k] = (unsigned short)l;
  }
}

// ---------------- final: (512,2), Q-MFMA -> in-reg softmax -> ctx-MFMA -> gelu -> out-conv MFMA -> LN1 ----------------
// (unchanged from round 5)
__launch_bounds__(512, 2)
__global__ void final_kernel(const float* __restrict__ fmap,
                             const float* __restrict__ g0,
                             const float* __restrict__ b0,
                             const float* __restrict__ g1,
                             const float* __restrict__ b1,
                             const float* __restrict__ ws,
                             float* __restrict__ out) {
  __shared__ float sm[14592];
  const int x = blockIdx.x, b = blockIdx.y, t = threadIdx.x;
  const int wave = t >> 6, lane = t & 63;
  const int ln = lane & 15, kb = lane >> 4;   // MFMA fragment coords
  const int or2 = wave >> 1, yc = wave & 1;   // wave tile: o-tiles(or head) x y-halves

  float* fmS = sm;            // [32][128] staging
  float* pls = sm + 4096;     // 3 planes x [128][20] staging splits
  float* gel = sm;            // 3 planes x [128][36] gel splits (aliases staging)
  float* muS = sm + 13824;
  float* rsS = sm + 13952;
  float* g0S = sm + 14080;
  float* b0S = sm + 14208;
  float* lnm = sm + 14336;
  float* lnr = sm + 14464;

  if (t < 128) {
    muS[t] = ws[OFF_MU + (unsigned)((b * 128 + t) * 128 + x)];
    rsS[t] = ws[OFF_RSTD + (unsigned)((b * 128 + t) * 128 + x)];
  } else if (t < 256) g0S[t - 128] = g0[t - 128];
  else if (t < 384) b0S[t - 256] = b0[t - 256];

  const unsigned short* wqspl = (const unsigned short*)(ws + OFF_WQSPL);
  const unsigned short* wospl = (const unsigned short*)(ws + OFF_WOSPL);
  const unsigned short* ctxp  = (const unsigned short*)(ws + OFF_CTXP);

  f32x4 oacc[2][4];
  #pragma unroll
  for (int i = 0; i < 2; ++i)
    #pragma unroll
    for (int j = 0; j < 4; ++j) oacc[i][j] = (f32x4){0.f, 0.f, 0.f, 0.f};

  for (int qblk = 0; qblk < 2; ++qblk) {
    f32x4 qacc[2][4];
    #pragma unroll
    for (int i = 0; i < 2; ++i)
      #pragma unroll
      for (int j = 0; j < 4; ++j) qacc[i][j] = (f32x4){0.f, 0.f, 0.f, 0.f};

    // ---- Q matmul over 4 c-chunks ----
    for (int cc = 0; cc < 4; ++cc) {
      bf16x8 af[2][3];
      #pragma unroll
      for (int ot = 0; ot < 2; ++ot)
        #pragma unroll
        for (int p = 0; p < 3; ++p)
          af[ot][p] = *(const bf16x8*)(wqspl + p * 32768 +
              ((qblk * 128 + or2 * 32 + ot * 16 + ln) * 128 + cc * 32 + kb * 8));

      __syncthreads();                          // staging region free of prior readers
      #pragma unroll
      for (int it = 0; it < 2; ++it) {          // stage fm chunk, LN0 applied (f32)
        int idx4 = it * 512 + t;
        int c = idx4 >> 5, y4 = (idx4 & 31) * 4;
        int cg = cc * 32 + c;
        const float4 r = *(const float4*)(fmap + (((size_t)(b * 128 + cg)) * 128 + x) * 128 + y4);
        float mu = muS[cg], rs = rsS[cg];
        float4 g = *(const float4*)(g0S + y4);
        float4 be = *(const float4*)(b0S + y4);
        float4 o;
        o.x = (r.x - mu) * rs * g.x + be.x;
        o.y = (r.y - mu) * rs * g.y + be.y;
        o.z = (r.z - mu) * rs * g.z + be.z;
        o.w = (r.w - mu) * rs * g.w + be.w;
        *(float4*)(fmS + c * 128 + y4) = o;
      }
      __syncthreads();
      {                                         // transpose + 3-way bf16 split
        const int ty = t & 127, cg = t >> 7;
        unsigned int d0[4], d1[4], d2[4];
        #pragma unroll
        for (int jj = 0; jj < 4; ++jj) {
          unsigned int h[2], m[2], l[2];
          #pragma unroll
          for (int e = 0; e < 2; ++e) {
            float v = fmS[(cg * 8 + jj * 2 + e) * 128 + ty];
            split3(v, h[e], m[e], l[e]);
          }
          d0[jj] = h[0] | (h[1] << 16);
          d1[jj] = m[0] | (m[1] << 16);
          d2[jj] = l[0] | (l[1] << 16);
        }
        float* pp = pls + ty * 20 + cg * 4;
        *reinterpret_cast<uint4*>(pp)        = make_uint4(d0[0], d0[1], d0[2], d0[3]);
        *reinterpret_cast<uint4*>(pp + 2560) = make_uint4(d1[0], d1[1], d1[2], d1[3]);
        *reinterpret_cast<uint4*>(pp + 5120) = make_uint4(d2[0], d2[1], d2[2], d2[3]);
      }
      __syncthreads();
      #pragma unroll
      for (int yt = 0; yt < 4; ++yt) {
        const float* bp = pls + ((yc * 4 + yt) * 16 + ln) * 20 + kb * 4;
        bf16x8 B0 = *(const bf16x8*)(bp);
        bf16x8 B1 = *(const bf16x8*)(bp + 2560);
        bf16x8 B2 = *(const bf16x8*)(bp + 5120);
        #pragma unroll
        for (int ot = 0; ot < 2; ++ot)
          qacc[ot][yt] = mfma6(af[ot][0], af[ot][1], af[ot][2], B0, B1, B2, qacc[ot][yt]);
      }
    }

    // ---- in-register exp + ssum (4-lane butterfly) + 3-split pack (sigma layout) ----
    float rssum[4];
    bf16x8 pf0[4], pf1[4], pf2[4];
    #pragma unroll
    for (int yt = 0; yt < 4; ++yt) {
      float pv[8];
      #pragma unroll
      for (int ot = 0; ot < 2; ++ot)
        #pragma unroll
        for (int r = 0; r < 4; ++r)
          pv[ot * 4 + r] = __expf(qacc[ot][yt][r]);
      float ps = ((pv[0] + pv[1]) + (pv[2] + pv[3])) + ((pv[4] + pv[5]) + (pv[6] + pv[7]));
      ps += __shfl_xor(ps, 16);
      ps += __shfl_xor(ps, 32);
      rssum[yt] = 1.0f / ps;
      unsigned wh[4], wm[4], wl[4];
      #pragma unroll
      for (int j = 0; j < 4; ++j) {
        unsigned h0, m0, l0, h1, m1, l1;
        split3(pv[2 * j], h0, m0, l0);
        split3(pv[2 * j + 1], h1, m1, l1);
        wh[j] = h0 | (h1 << 16);
        wm[j] = m0 | (m1 << 16);
        wl[j] = l0 | (l1 << 16);
      }
      uint4 uh = make_uint4(wh[0], wh[1], wh[2], wh[3]);
      uint4 um = make_uint4(wm[0], wm[1], wm[2], wm[3]);
      uint4 ul = make_uint4(wl[0], wl[1], wl[2], wl[3]);
      pf0[yt] = *(const bf16x8*)&uh;
      pf1[yt] = *(const bf16x8*)&um;
      pf2[yt] = *(const bf16x8*)&ul;
    }

    // ---- ge[e][y] = sum_d ctx[d][e] * exp(q[d][y]) via MFMA (A from L2, B in-reg) ----
    f32x4 ge[2][4];
    const unsigned short* chp = ctxp + (size_t)(b * 8 + qblk * 4 + or2) * 3072;
    #pragma unroll
    for (int ot = 0; ot < 2; ++ot) {
      bf16x8 aq0 = *(const bf16x8*)(chp +        (ot * 16 + ln) * 32 + kb * 8);
      bf16x8 aq1 = *(const bf16x8*)(chp + 1024 + (ot * 16 + ln) * 32 + kb * 8);
      bf16x8 aq2 = *(const bf16x8*)(chp + 2048 + (ot * 16 + ln) * 32 + kb * 8);
      #pragma unroll
      for (int yt = 0; yt < 4; ++yt) {
        f32x4 c = (f32x4){0.f, 0.f, 0.f, 0.f};
        ge[ot][yt] = mfma6(aq0, aq1, aq2, pf0[yt], pf1[yt], pf2[yt], c);
      }
    }

    // ---- gelu in-register ----
    #pragma unroll
    for (int ot = 0; ot < 2; ++ot)
      #pragma unroll
      for (int yt = 0; yt < 4; ++yt)
        #pragma unroll
        for (int r = 0; r < 4; ++r) {
          float v = ge[ot][yt][r] * rssum[yt];
          ge[ot][yt][r] = 0.5f * v * (1.0f + erff(v * 0.70710678118654752f));
        }

    // ---- out-conv in 2 phases of K=64 (heads {2ph, 2ph+1}) ----
    for (int ph = 0; ph < 2; ++ph) {
      __syncthreads();                          // prior readers of gel region done
      if ((or2 >> 1) == ph) {                   // this wave's head is in the chunk
        const int c16 = (or2 & 1) * 16;
        #pragma unroll
        for (int yt = 0; yt < 4; ++yt) {
          float* grow = gel + ((yc * 4 + yt) * 16 + ln) * 36 + c16 + kb * 4;
          #pragma unroll
          for (int ot = 0; ot < 2; ++ot) {
            unsigned h0, m0, l0, h1, m1, l1, h2, m2, l2, h3, m3, l3;
            split3(ge[ot][yt][0], h0, m0, l0);
            split3(ge[ot][yt][1], h1, m1, l1);
            split3(ge[ot][yt][2], h2, m2, l2);
            split3(ge[ot][yt][3], h3, m3, l3);
            *(uint2*)(grow + ot * 2)        = make_uint2(h0 | (h1 << 16), h2 | (h3 << 16));
            *(uint2*)(grow + 4608 + ot * 2) = make_uint2(m0 | (m1 << 16), m2 | (m3 << 16));
            *(uint2*)(grow + 9216 + ot * 2) = make_uint2(l0 | (l1 << 16), l2 | (l3 << 16));
          }
        }
      }
      __syncthreads();                          // gel planes visible
      #pragma unroll
      for (int kc = 0; kc < 2; ++kc) {
        bf16x8 ao[2][3];
        #pragma unroll
        for (int ot = 0; ot < 2; ++ot)
          #pragma unroll
          for (int p = 0; p < 3; ++p)
            ao[ot][p] = *(const bf16x8*)(wospl + p * 32768 +
                ((or2 * 32 + ot * 16 + ln) * 256 + qblk * 128 + ph * 64 + kc * 32 + kb * 8));
        #pragma unroll
        for (int yt = 0; yt < 4; ++yt) {
          const float* bp = gel + ((yc * 4 + yt) * 16 + ln) * 36 + kc * 16 + kb * 4;
          bf16x8 B0 = *(const bf16x8*)(bp);
          bf16x8 B1 = *(const bf16x8*)(bp + 4608);
          bf16x8 B2 = *(const bf16x8*)(bp + 9216);
          #pragma unroll
          for (int ot = 0; ot < 2; ++ot)
            oacc[ot][yt] = mfma6(ao[ot][0], ao[ot][1], ao[ot][2], B0, B1, B2, oacc[ot][yt]);
        }
      }
    }
  }

  // ---- LN1 over y per o-row ----
  __syncthreads();
  float* red_s = sm;
  float* red_q = sm + 4096;
  #pragma unroll
  for (int ot = 0; ot < 2; ++ot)
    #pragma unroll
    for (int r = 0; r < 4; ++r) {
      int o = or2 * 32 + ot * 16 + kb * 4 + r;
      float s = 0.0f, q = 0.0f;
      #pragma unroll
      for (int yt = 0; yt < 4; ++yt) { float v = oacc[ot][yt][r]; s += v; q = fmaf(v, v, q); }
      red_s[o * 32 + yc * 16 + ln] = s;
      red_q[o * 32 + yc * 16 + ln] = q;
    }
  __syncthreads();
  if (t < 128) {
    double s = 0.0, q = 0.0;
    #pragma unroll
    for (int i = 0; i < 32; ++i) { s += red_s[t * 32 + i]; q += red_q[t * 32 + i]; }
    double mu = s * (1.0 / 128.0);
    double var = q * (1.0 / 128.0) - mu * mu;
    lnm[t] = (float)mu;
    lnr[t] = (float)(1.0 / sqrt(var + 1e-5));
  }
  __syncthreads();
  float g1v[4], b1v[4];
  #pragma unroll
  for (int yt = 0; yt < 4; ++yt) {
    int y = (yc * 4 + yt) * 16 + ln;
    g1v[yt] = g1[y]; b1v[yt] = b1[y];
  }
  #pragma unroll
  for (int ot = 0; ot < 2; ++ot)
    #pragma unroll
    for (int r = 0; r < 4; ++r) {
      int o = or2 * 32 + ot * 16 + kb * 4 + r;
      float mu = lnm[o], rs = lnr[o];
      #pragma unroll
      for (int yt = 0; yt < 4; ++yt) {
        int y = (yc * 4 + yt) * 16 + ln;
        out[(((size_t)(b * 128 + o)) * 128 + x) * 128 + y] =
            (oacc[ot][yt][r] - mu) * rs * g1v[yt] + b1v[yt];
      }
    }
}

extern "C" void kernel_launch(void* const* d_in, const int* in_sizes, int n_in,
                              void* d_out, int out_size, void* d_ws, size_t ws_size,
                              hipStream_t stream) {
  const float* fmap = (const float*)d_in[0];
  const float* g0   = (const float*)d_in[1];
  const float* b0   = (const float*)d_in[2];
  const float* wqkv = (const float*)d_in[3];
  const float* wout = (const float*)d_in[4];
  const float* g1   = (const float*)d_in[5];
  const float* b1   = (const float*)d_in[6];
  float* ws  = (float*)d_ws;
  float* out = (float*)d_out;

  hipMemsetAsync((char*)d_ws + (size_t)OFF_CTXA * 4, 0, (size_t)2162688 * 4, stream);
  prep_kernel<<<512, 256, 0, stream>>>(wqkv, wout, ws);
  kv_ctx_kernel<<<dim3(128, 16), 512, 0, stream>>>(fmap, g0, b0, ws);
  ctx_reduce_kernel<<<128, 256, 0, stream>>>(ws);
  final_kernel<<<dim3(128, 16), 512, 0, stream>>>(fmap, g0, b0, g1, b1, ws, out);
}